// Round 1
// baseline (601.980 us; speedup 1.0000x reference)
//
#include <hip/hip_runtime.h>
#include <string.h>

// ---------------- problem constants ----------------
#define T_LEN   809
#define DD      304
#define EE      300
#define LQ      30
#define NCAND   12824      // candidates per batch
#define NPAD    12928      // 101 * 128 (padded rows per chunk)
#define MTILES  101
#define KP      1216       // 1212 padded to mult of 32
#define CIN     1212
#define H1      1024
#define H2      512
#define BATCH   4

// alpha^(span+1), span in [0,16)
__device__ __constant__ float c_coef[16] = {
  0.9f, 0.81f, 0.729f, 0.6561f, 0.59049f, 0.531441f, 0.4782969f, 0.43046721f,
  0.387420489f, 0.3486784401f, 0.31381059609f, 0.282429536481f,
  0.2541865828329f, 0.22876792454961f, 0.205891132094649f, 0.1853020188851841f
};

__device__ __forceinline__ unsigned short f2bf(float f) {
  unsigned int u = __float_as_uint(f);
  u += 0x7fffu + ((u >> 16) & 1u);          // round-to-nearest-even
  return (unsigned short)(u >> 16);
}
__device__ __forceinline__ float bf2f(unsigned short h) {
  return __uint_as_float(((unsigned int)h) << 16);
}

typedef const __attribute__((address_space(1))) unsigned int GU32;
typedef __attribute__((address_space(3))) unsigned int LU32;
__device__ __forceinline__ void async16(const unsigned short* g, unsigned short* l) {
  __builtin_amdgcn_global_load_lds((GU32*)g, (LU32*)l, 16, 0, 0);
}

// ---------------- F / R decay scans (chunked, 192-step lookback) ----------------
// F[t] = doc[t] + a*F[t-1]; R[t] = doc[t] + a*R[t+1]. alpha^192 ~ 1.6e-9 -> exact enough.
__global__ __launch_bounds__(320) void k_scan(const float* __restrict__ doc,
                                              float* __restrict__ F,
                                              float* __restrict__ R)
{
  const int d  = threadIdx.x;
  if (d >= DD) return;
  const int t0 = blockIdx.x * 32;
  const int b  = blockIdx.y;
  const float* db = doc + (size_t)b * T_LEN * DD + d;
  if (blockIdx.z == 0) {
    int start = t0 - 192; if (start < 0) start = 0;
    int end = t0 + 31; if (end > T_LEN - 1) end = T_LEN - 1;
    float s = 0.f;
    for (int t = start; t <= end; ++t) {
      s = fmaf(0.9f, s, db[(size_t)t * DD]);
      if (t >= t0) F[((size_t)b * T_LEN + t) * DD + d] = s;
    }
  } else {
    int t1 = t0 + 31; if (t1 > T_LEN - 1) t1 = T_LEN - 1;
    int start = t1 + 192; if (start > T_LEN - 1) start = T_LEN - 1;
    float s = 0.f;
    for (int t = start; t >= t0; --t) {
      s = fmaf(0.9f, s, db[(size_t)t * DD]);
      if (t <= t1) R[((size_t)b * T_LEN + t) * DD + d] = s;
    }
  }
}

// ---------------- query FOFE: qf[b][d] = sum_t alpha^(29-t) q[b][t][d] ----------------
__global__ __launch_bounds__(320) void k_qf(const float* __restrict__ q, float* __restrict__ qf)
{
  const int d = threadIdx.x;
  const int b = blockIdx.x;
  if (d >= EE) return;
  float s = 0.f;
  for (int t = 0; t < LQ; ++t) s = fmaf(s, 0.9f, q[((size_t)b * LQ + t) * EE + d]);
  qf[b * EE + d] = s;
}

// ---------------- BN-folded weight prep (fp32 -> bf16) ----------------
__global__ __launch_bounds__(64) void k_w1(const float* __restrict__ W1, const float* __restrict__ g1,
                                           const float* __restrict__ v1, unsigned short* __restrict__ W1b)
{
  const int k = blockIdx.x * 64 + threadIdx.x;   // 0..1215
  const int j = blockIdx.y;                      // 0..1023
  float w = 0.f;
  if (k < CIN) w = W1[(size_t)j * CIN + k] * g1[j] * rsqrtf(v1[j] + 1e-5f);
  W1b[(size_t)j * KP + k] = f2bf(w);
}
__global__ __launch_bounds__(64) void k_w2(const float* __restrict__ W2, const float* __restrict__ g2,
                                           const float* __restrict__ v2, unsigned short* __restrict__ W2b)
{
  const int k = blockIdx.x * 64 + threadIdx.x;   // 0..1023
  const int j = blockIdx.y;                      // 0..511
  float w = W2[(size_t)j * H1 + k] * g2[j] * rsqrtf(v2[j] + 1e-5f);
  W2b[(size_t)j * H1 + k] = f2bf(w);
}
__global__ __launch_bounds__(256) void k_bias(const float* g1, const float* b1, const float* m1, const float* v1,
                                              const float* g2, const float* b2, const float* m2, const float* v2,
                                              float* bias1, float* bias2)
{
  const int i = blockIdx.x * 256 + threadIdx.x;
  if (i < H1) {
    float s = g1[i] * rsqrtf(v1[i] + 1e-5f);
    bias1[i] = b1[i] - m1[i] * s;
  } else if (i < H1 + H2) {
    int j = i - H1;
    float s = g2[j] * rsqrtf(v2[j] + 1e-5f);
    bias2[j] = b2[j] - m2[j] * s;
  }
}

// ---------------- build X (bf16, row-major NPAD x KP) for one batch chunk ----------------
// k-layout: [0,304)=lctx  [304,608)=cand  [608,912)=rctx  [912,1212)=qf  [1212,1216)=0
__global__ __launch_bounds__(256) void k_build_x(const float* __restrict__ F, const float* __restrict__ R,
                                                 const float* __restrict__ qf, unsigned short* __restrict__ X,
                                                 int b)
{
  const int flat = blockIdx.x * 256 + threadIdx.x;     // over NPAD*304 groups of 4 k's
  if (flat >= NPAD * 304) return;
  const int row = flat / 304;
  const int g = flat - row * 304;
  float v0 = 0.f, v1 = 0.f, v2 = 0.f, v3 = 0.f;
  if (row < NCAND) {
    int s, span;
    if (row < 12704) { s = row >> 4; span = row & 15; }
    else {
      int m = row - 12704; int j = 0, off = 0;
      while (off + (15 - j) <= m) { off += 15 - j; ++j; }
      s = 794 + j; span = m - off;
    }
    const int e = s + span;
    const float* Fb = F + (size_t)b * T_LEN * DD;
    const float* Rb = R + (size_t)b * T_LEN * DD;
    if (g < 76) {                       // lctx = F[s-1] (0 if s==0)
      const int d = g * 4;
      if (s > 0) { float4 t = *(const float4*)(Fb + (size_t)(s - 1) * DD + d); v0=t.x; v1=t.y; v2=t.z; v3=t.w; }
    } else if (g < 152) {               // cand = F[e] - coef*F[s-1]
      const int d = (g - 76) * 4;
      float4 fe = *(const float4*)(Fb + (size_t)e * DD + d);
      float4 fs = make_float4(0.f, 0.f, 0.f, 0.f);
      if (s > 0) fs = *(const float4*)(Fb + (size_t)(s - 1) * DD + d);
      const float c = c_coef[span];
      v0 = fe.x - c * fs.x; v1 = fe.y - c * fs.y; v2 = fe.z - c * fs.z; v3 = fe.w - c * fs.w;
    } else if (g < 228) {               // rctx = R[e+1] (0 if e+1==T)
      const int d = (g - 152) * 4;
      if (e + 1 < T_LEN) { float4 t = *(const float4*)(Rb + (size_t)(e + 1) * DD + d); v0=t.x; v1=t.y; v2=t.z; v3=t.w; }
    } else if (g < 303) {               // qf
      const int d = (g - 228) * 4;
      float4 t = *(const float4*)(qf + b * EE + d);
      v0 = t.x; v1 = t.y; v2 = t.z; v3 = t.w;
    }                                   // g==303: K padding -> zeros
  }
  ushort4 o;
  o.x = f2bf(v0); o.y = f2bf(v1); o.z = f2bf(v2); o.w = f2bf(v3);
  *(ushort4*)(X + (size_t)row * KP + g * 4) = o;
}

// ---------------- bf16 GEMM (m97 pattern): C = relu(A * Bw^T + bias) -> bf16 ----------------
// A: (NPAD x K) bf16 row-major. Bw: (Nout x K) bf16 row-major. C: (NPAD x Nout) bf16.
// 128x128 tile, BK=32, 4 waves of 64x64, global_load_lds width 16.
typedef __attribute__((ext_vector_type(8))) short frag8;
typedef __attribute__((ext_vector_type(4))) float f32x4;

__global__ __launch_bounds__(256) void k_gemm(const unsigned short* __restrict__ A,
                                              const unsigned short* __restrict__ Bw,
                                              const float* __restrict__ bias,
                                              unsigned short* __restrict__ C,
                                              int K, int Nout)
{
  __shared__ __align__(16) unsigned short As[128 * 32];
  __shared__ __align__(16) unsigned short Bs[128 * 32];
  const int tid  = threadIdx.x;
  const int lane = tid & 63;
  const int wv   = tid >> 6;
  const int wm   = wv & 1, wn = wv >> 1;
  const int bn   = blockIdx.x, bm = blockIdx.y;

  // staging: wave wv stages rows [wv*32, wv*32+32) of both tiles, 2 issues of 16 rows
  const int lr = lane >> 2;          // row within 16-row group
  const int lc = lane & 3;           // 16B chunk within 64B row
  const size_t rowA = (size_t)bm * 128 + wv * 32 + lr;
  const size_t rowB = (size_t)bn * 128 + wv * 32 + lr;
  const unsigned short* gA = A + rowA * K + lc * 8;
  const unsigned short* gB = Bw + rowB * K + lc * 8;
  const size_t row16 = (size_t)16 * K;
  unsigned short* lA0 = &As[wv * 1024];
  unsigned short* lB0 = &Bs[wv * 1024];

  f32x4 acc[4][4];
  #pragma unroll
  for (int i = 0; i < 4; ++i)
    #pragma unroll
    for (int j = 0; j < 4; ++j) acc[i][j] = (f32x4){0.f, 0.f, 0.f, 0.f};

  const int aoff = (wm * 64 + (lane & 15)) * 32 + (lane >> 4) * 8;
  const int boff = (wn * 64 + (lane & 15)) * 32 + (lane >> 4) * 8;

  for (int kc = 0; kc < K; kc += 32) {
    __syncthreads();                       // previous compute done with LDS
    async16(gA + kc,         lA0);
    async16(gA + kc + row16, lA0 + 512);
    async16(gB + kc,         lB0);
    async16(gB + kc + row16, lB0 + 512);
    __syncthreads();                       // barrier drains vmcnt -> tiles resident

    frag8 a[4], b[4];
    #pragma unroll
    for (int i = 0; i < 4; ++i) a[i] = *(const frag8*)&As[aoff + i * 512];
    #pragma unroll
    for (int i = 0; i < 4; ++i) b[i] = *(const frag8*)&Bs[boff + i * 512];
    #pragma unroll
    for (int i = 0; i < 4; ++i)
      #pragma unroll
      for (int j = 0; j < 4; ++j)
        acc[i][j] = __builtin_amdgcn_mfma_f32_16x16x32_bf16(a[i], b[j], acc[i][j], 0, 0, 0);
  }

  // epilogue: bias + relu -> bf16.  C/D map: col = lane&15, row = (lane>>4)*4 + reg
  const int crow0 = bm * 128 + wm * 64 + ((lane >> 4) << 2);
  const int ccol0 = bn * 128 + wn * 64 + (lane & 15);
  #pragma unroll
  for (int i = 0; i < 4; ++i) {
    #pragma unroll
    for (int j = 0; j < 4; ++j) {
      const int col = ccol0 + j * 16;
      const float bj = bias[col];
      #pragma unroll
      for (int r = 0; r < 4; ++r) {
        const int row = crow0 + i * 16 + r;
        float v = acc[i][j][r] + bj;
        v = v > 0.f ? v : 0.f;
        C[(size_t)row * Nout + col] = f2bf(v);
      }
    }
  }
}

// ---------------- final layer: out[row][j] = sum_k h2[row][k] * W3[j][k] ----------------
__global__ __launch_bounds__(256) void k_out(const unsigned short* __restrict__ h2,
                                             const float* __restrict__ W3,
                                             float* __restrict__ out, int base)
{
  const int r = blockIdx.x * 4 + (threadIdx.x >> 6);
  const int lane = threadIdx.x & 63;
  if (r >= NCAND) return;
  const unsigned short* hp = h2 + (size_t)r * H2 + lane * 8;
  uint4 hv = *(const uint4*)hp;
  float hf[8];
  hf[0] = bf2f(hv.x & 0xffff); hf[1] = bf2f(hv.x >> 16);
  hf[2] = bf2f(hv.y & 0xffff); hf[3] = bf2f(hv.y >> 16);
  hf[4] = bf2f(hv.z & 0xffff); hf[5] = bf2f(hv.z >> 16);
  hf[6] = bf2f(hv.w & 0xffff); hf[7] = bf2f(hv.w >> 16);
  const int k = lane * 8;
  float d0 = 0.f, d1 = 0.f;
  #pragma unroll
  for (int i = 0; i < 8; ++i) {
    d0 = fmaf(hf[i], W3[k + i], d0);
    d1 = fmaf(hf[i], W3[H2 + k + i], d1);
  }
  #pragma unroll
  for (int off = 32; off; off >>= 1) {
    d0 += __shfl_down(d0, off);
    d1 += __shfl_down(d1, off);
  }
  if (lane == 0) {
    out[(size_t)(base + r) * 2]     = d0;
    out[(size_t)(base + r) * 2 + 1] = d1;
  }
}

// ---------------- launch ----------------
extern "C" void kernel_launch(void* const* d_in, const int* in_sizes, int n_in,
                              void* d_out, int out_size, void* d_ws, size_t ws_size,
                              hipStream_t stream)
{
  const float* doc = (const float*)d_in[0];
  const float* qe  = (const float*)d_in[1];
  const float* W1  = (const float*)d_in[2];
  const float* g1  = (const float*)d_in[3];
  const float* b1  = (const float*)d_in[4];
  const float* m1  = (const float*)d_in[5];
  const float* v1  = (const float*)d_in[6];
  const float* W2  = (const float*)d_in[7];
  const float* g2  = (const float*)d_in[8];
  const float* b2  = (const float*)d_in[9];
  const float* m2  = (const float*)d_in[10];
  const float* v2  = (const float*)d_in[11];
  const float* W3  = (const float*)d_in[12];
  float* out = (float*)d_out;

  char* ws = (char*)d_ws;
  size_t off = 0;
  auto alloc = [&](size_t bytes) -> void* {
    void* p = ws + off;
    off = (off + bytes + 255) & ~(size_t)255;
    return p;
  };
  float*          F     = (float*)alloc((size_t)BATCH * T_LEN * DD * 4);
  float*          R     = (float*)alloc((size_t)BATCH * T_LEN * DD * 4);
  float*          qfbuf = (float*)alloc((size_t)BATCH * EE * 4);
  unsigned short* W1b   = (unsigned short*)alloc((size_t)H1 * KP * 2);
  float*          bias1 = (float*)alloc((size_t)H1 * 4);
  unsigned short* W2b   = (unsigned short*)alloc((size_t)H2 * H1 * 2);
  float*          bias2 = (float*)alloc((size_t)H2 * 4);
  unsigned short* X     = (unsigned short*)alloc((size_t)NPAD * KP * 2);
  unsigned short* h1    = (unsigned short*)alloc((size_t)NPAD * H1 * 2);
  unsigned short* h2    = (unsigned short*)alloc((size_t)NPAD * H2 * 2);

  k_scan<<<dim3(26, BATCH, 2), 320, 0, stream>>>(doc, F, R);
  k_qf<<<dim3(BATCH), 320, 0, stream>>>(qe, qfbuf);
  k_w1<<<dim3(19, H1), 64, 0, stream>>>(W1, g1, v1, W1b);
  k_w2<<<dim3(16, H2), 64, 0, stream>>>(W2, g2, v2, W2b);
  k_bias<<<dim3(6), 256, 0, stream>>>(g1, b1, m1, v1, g2, b2, m2, v2, bias1, bias2);

  for (int b = 0; b < BATCH; ++b) {
    k_build_x<<<dim3(NPAD * 304 / 256), 256, 0, stream>>>(F, R, qfbuf, X, b);
    k_gemm<<<dim3(H1 / 128, MTILES), 256, 0, stream>>>(X, W1b, bias1, h1, KP, H1);
    k_gemm<<<dim3(H2 / 128, MTILES), 256, 0, stream>>>(h1, W2b, bias2, h2, H1, H2);
    k_out<<<dim3(NCAND / 4), 256, 0, stream>>>(h2, W3, out, b * NCAND);
  }
}

// Round 2
// 479.090 us; speedup vs baseline: 1.2565x; 1.2565x over previous
//
#include <hip/hip_runtime.h>
#include <string.h>

// ---------------- problem constants ----------------
#define T_LEN   809
#define DD      304
#define EE      300
#define LQ      30
#define NCAND   12824      // candidates per batch
#define NPAD    12928      // 101 * 128 (padded rows per batch)
#define KP      1216       // 1212 padded to mult of 32
#define CIN     1212
#define H1      1024
#define H2      512
#define BATCH   4
#define MROWS_F (BATCH * NPAD)          // 51712 fused rows
#define MT_F    (MROWS_F / 128)         // 404
#define MT_1    (NPAD / 128)            // 101

// alpha^(span+1), span in [0,16)
__device__ __constant__ float c_coef[16] = {
  0.9f, 0.81f, 0.729f, 0.6561f, 0.59049f, 0.531441f, 0.4782969f, 0.43046721f,
  0.387420489f, 0.3486784401f, 0.31381059609f, 0.282429536481f,
  0.2541865828329f, 0.22876792454961f, 0.205891132094649f, 0.1853020188851841f
};

__device__ __forceinline__ unsigned short f2bf(float f) {
  unsigned int u = __float_as_uint(f);
  u += 0x7fffu + ((u >> 16) & 1u);          // round-to-nearest-even
  return (unsigned short)(u >> 16);
}

typedef const __attribute__((address_space(1))) unsigned int GU32;
typedef __attribute__((address_space(3))) unsigned int LU32;
__device__ __forceinline__ void async16(const unsigned short* g, unsigned short* l) {
  __builtin_amdgcn_global_load_lds((GU32*)g, (LU32*)l, 16, 0, 0);
}

// ---------------- F / R decay scans (chunked, 192-step lookback) ----------------
__global__ __launch_bounds__(320) void k_scan(const float* __restrict__ doc,
                                              float* __restrict__ F,
                                              float* __restrict__ R)
{
  const int d  = threadIdx.x;
  if (d >= DD) return;
  const int t0 = blockIdx.x * 32;
  const int b  = blockIdx.y;
  const float* db = doc + (size_t)b * T_LEN * DD + d;
  if (blockIdx.z == 0) {
    int start = t0 - 192; if (start < 0) start = 0;
    int end = t0 + 31; if (end > T_LEN - 1) end = T_LEN - 1;
    float s = 0.f;
    for (int t = start; t <= end; ++t) {
      s = fmaf(0.9f, s, db[(size_t)t * DD]);
      if (t >= t0) F[((size_t)b * T_LEN + t) * DD + d] = s;
    }
  } else {
    int t1 = t0 + 31; if (t1 > T_LEN - 1) t1 = T_LEN - 1;
    int start = t1 + 192; if (start > T_LEN - 1) start = T_LEN - 1;
    float s = 0.f;
    for (int t = start; t >= t0; --t) {
      s = fmaf(0.9f, s, db[(size_t)t * DD]);
      if (t <= t1) R[((size_t)b * T_LEN + t) * DD + d] = s;
    }
  }
}

// ---------------- query FOFE ----------------
__global__ __launch_bounds__(320) void k_qf(const float* __restrict__ q, float* __restrict__ qf)
{
  const int d = threadIdx.x;
  const int b = blockIdx.x;
  if (d >= EE) return;
  float s = 0.f;
  for (int t = 0; t < LQ; ++t) s = fmaf(s, 0.9f, q[((size_t)b * LQ + t) * EE + d]);
  qf[b * EE + d] = s;
}

// ---------------- BN-folded weight prep (fp32 -> bf16) ----------------
__global__ __launch_bounds__(64) void k_w1(const float* __restrict__ W1, const float* __restrict__ g1,
                                           const float* __restrict__ v1, unsigned short* __restrict__ W1b)
{
  const int k = blockIdx.x * 64 + threadIdx.x;
  const int j = blockIdx.y;
  float w = 0.f;
  if (k < CIN) w = W1[(size_t)j * CIN + k] * g1[j] * rsqrtf(v1[j] + 1e-5f);
  W1b[(size_t)j * KP + k] = f2bf(w);
}
__global__ __launch_bounds__(64) void k_w2(const float* __restrict__ W2, const float* __restrict__ g2,
                                           const float* __restrict__ v2, unsigned short* __restrict__ W2b)
{
  const int k = blockIdx.x * 64 + threadIdx.x;
  const int j = blockIdx.y;
  float w = W2[(size_t)j * H1 + k] * g2[j] * rsqrtf(v2[j] + 1e-5f);
  W2b[(size_t)j * H1 + k] = f2bf(w);
}
__global__ __launch_bounds__(256) void k_bias(const float* g1, const float* b1, const float* m1, const float* v1,
                                              const float* g2, const float* b2, const float* m2, const float* v2,
                                              float* bias1, float* bias2)
{
  const int i = blockIdx.x * 256 + threadIdx.x;
  if (i < H1) {
    float s = g1[i] * rsqrtf(v1[i] + 1e-5f);
    bias1[i] = b1[i] - m1[i] * s;
  } else if (i < H1 + H2) {
    int j = i - H1;
    float s = g2[j] * rsqrtf(v2[j] + 1e-5f);
    bias2[j] = b2[j] - m2[j] * s;
  }
}

// ---------------- zero the output (atomics accumulate into it) ----------------
__global__ __launch_bounds__(256) void k_zero_out(float* __restrict__ out, int n)
{
  const int i = blockIdx.x * 256 + threadIdx.x;
  if (i < n) out[i] = 0.f;
}

// ---------------- build X (bf16, row-major nrow x KP) ----------------
// k-layout: [0,304)=lctx  [304,608)=cand  [608,912)=rctx  [912,1212)=qf  [1212,1216)=0
__global__ __launch_bounds__(256) void k_build_x(const float* __restrict__ F, const float* __restrict__ R,
                                                 const float* __restrict__ qf, unsigned short* __restrict__ X,
                                                 int nrow, int b0)
{
  const int flat = blockIdx.x * 256 + threadIdx.x;
  if (flat >= nrow * 304) return;
  const int row = flat / 304;
  const int g = flat - row * 304;
  const int b = b0 + row / NPAD;
  const int r = row % NPAD;
  float v0 = 0.f, v1 = 0.f, v2 = 0.f, v3 = 0.f;
  if (r < NCAND) {
    int s, span;
    if (r < 12704) { s = r >> 4; span = r & 15; }
    else {
      int m = r - 12704; int j = 0, off = 0;
      while (off + (15 - j) <= m) { off += 15 - j; ++j; }
      s = 794 + j; span = m - off;
    }
    const int e = s + span;
    const float* Fb = F + (size_t)b * T_LEN * DD;
    const float* Rb = R + (size_t)b * T_LEN * DD;
    if (g < 76) {
      const int d = g * 4;
      if (s > 0) { float4 t = *(const float4*)(Fb + (size_t)(s - 1) * DD + d); v0=t.x; v1=t.y; v2=t.z; v3=t.w; }
    } else if (g < 152) {
      const int d = (g - 76) * 4;
      float4 fe = *(const float4*)(Fb + (size_t)e * DD + d);
      float4 fs = make_float4(0.f, 0.f, 0.f, 0.f);
      if (s > 0) fs = *(const float4*)(Fb + (size_t)(s - 1) * DD + d);
      const float c = c_coef[span];
      v0 = fe.x - c * fs.x; v1 = fe.y - c * fs.y; v2 = fe.z - c * fs.z; v3 = fe.w - c * fs.w;
    } else if (g < 228) {
      const int d = (g - 152) * 4;
      if (e + 1 < T_LEN) { float4 t = *(const float4*)(Rb + (size_t)(e + 1) * DD + d); v0=t.x; v1=t.y; v2=t.z; v3=t.w; }
    } else if (g < 303) {
      const int d = (g - 228) * 4;
      float4 t = *(const float4*)(qf + b * EE + d);
      v0 = t.x; v1 = t.y; v2 = t.z; v3 = t.w;
    }
  }
  ushort4 o;
  o.x = f2bf(v0); o.y = f2bf(v1); o.z = f2bf(v2); o.w = f2bf(v3);
  *(ushort4*)(X + (size_t)row * KP + g * 4) = o;
}

// ---------------- bf16 GEMM (m97 pattern): C = relu(A * Bw^T + bias) -> bf16 ----------------
typedef __attribute__((ext_vector_type(8))) short frag8;
typedef __attribute__((ext_vector_type(4))) float f32x4;

// shared K-loop body: fills acc[4][4] for a 128x128 tile
#define GEMM_BODY(A_, B_, K_)                                                    \
  __shared__ __align__(16) unsigned short As[128 * 32];                          \
  __shared__ __align__(16) unsigned short Bs[128 * 32];                          \
  const int tid  = threadIdx.x;                                                  \
  const int lane = tid & 63;                                                     \
  const int wv   = tid >> 6;                                                     \
  const int wm   = wv & 1, wn = wv >> 1;                                         \
  const int bn   = blockIdx.x, bm = blockIdx.y;                                  \
  const int lr = lane >> 2;                                                      \
  const int lc = lane & 3;                                                       \
  const size_t rowA = (size_t)bm * 128 + wv * 32 + lr;                           \
  const size_t rowB = (size_t)bn * 128 + wv * 32 + lr;                           \
  const unsigned short* gA = A_ + rowA * K_ + lc * 8;                            \
  const unsigned short* gB = B_ + rowB * K_ + lc * 8;                            \
  const size_t row16 = (size_t)16 * K_;                                          \
  unsigned short* lA0 = &As[wv * 1024];                                          \
  unsigned short* lB0 = &Bs[wv * 1024];                                          \
  f32x4 acc[4][4];                                                               \
  _Pragma("unroll")                                                              \
  for (int i = 0; i < 4; ++i)                                                    \
    _Pragma("unroll")                                                            \
    for (int j = 0; j < 4; ++j) acc[i][j] = (f32x4){0.f, 0.f, 0.f, 0.f};         \
  const int aoff = (wm * 64 + (lane & 15)) * 32 + (lane >> 4) * 8;               \
  const int boff = (wn * 64 + (lane & 15)) * 32 + (lane >> 4) * 8;               \
  for (int kc = 0; kc < K_; kc += 32) {                                          \
    __syncthreads();                                                             \
    async16(gA + kc,         lA0);                                               \
    async16(gA + kc + row16, lA0 + 512);                                         \
    async16(gB + kc,         lB0);                                               \
    async16(gB + kc + row16, lB0 + 512);                                         \
    __syncthreads();                                                             \
    frag8 a[4], b[4];                                                            \
    _Pragma("unroll")                                                            \
    for (int i = 0; i < 4; ++i) a[i] = *(const frag8*)&As[aoff + i * 512];       \
    _Pragma("unroll")                                                            \
    for (int i = 0; i < 4; ++i) b[i] = *(const frag8*)&Bs[boff + i * 512];       \
    _Pragma("unroll")                                                            \
    for (int i = 0; i < 4; ++i)                                                  \
      _Pragma("unroll")                                                          \
      for (int j = 0; j < 4; ++j)                                                \
        acc[i][j] = __builtin_amdgcn_mfma_f32_16x16x32_bf16(a[i], b[j], acc[i][j], 0, 0, 0); \
  }

// GEMM1: writes C (bf16) with bias+relu
__global__ __launch_bounds__(256) void k_gemm(const unsigned short* __restrict__ A,
                                              const unsigned short* __restrict__ Bw,
                                              const float* __restrict__ bias,
                                              unsigned short* __restrict__ C,
                                              int K, int Nout)
{
  GEMM_BODY(A, Bw, K)
  const int crow0 = bm * 128 + wm * 64 + ((lane >> 4) << 2);
  const int ccol0 = bn * 128 + wn * 64 + (lane & 15);
  #pragma unroll
  for (int i = 0; i < 4; ++i) {
    #pragma unroll
    for (int j = 0; j < 4; ++j) {
      const int col = ccol0 + j * 16;
      const float bj = bias[col];
      #pragma unroll
      for (int r = 0; r < 4; ++r) {
        const int row = crow0 + i * 16 + r;
        float v = acc[i][j][r] + bj;
        v = v > 0.f ? v : 0.f;
        C[(size_t)row * Nout + col] = f2bf(v);
      }
    }
  }
}

// GEMM2 with fused final layer: out[brow][jj] += relu(h2)·W3[jj]  (atomics)
__global__ __launch_bounds__(256) void k_gemm2_out(const unsigned short* __restrict__ A,
                                                   const unsigned short* __restrict__ Bw,
                                                   const float* __restrict__ bias,
                                                   const float* __restrict__ W3,
                                                   float* __restrict__ out,
                                                   int K, int pad_base)
{
  GEMM_BODY(A, Bw, K)
  const int crow0 = bm * 128 + wm * 64 + ((lane >> 4) << 2);
  const int ccol0 = bn * 128 + wn * 64 + (lane & 15);
  float w0[4], w1[4], bj[4];
  #pragma unroll
  for (int j = 0; j < 4; ++j) {
    const int col = ccol0 + j * 16;
    bj[j] = bias[col];
    w0[j] = W3[col];
    w1[j] = W3[H2 + col];
  }
  #pragma unroll
  for (int i = 0; i < 4; ++i) {
    #pragma unroll
    for (int r = 0; r < 4; ++r) {
      float p0 = 0.f, p1 = 0.f;
      #pragma unroll
      for (int j = 0; j < 4; ++j) {
        float v = acc[i][j][r] + bj[j];
        v = v > 0.f ? v : 0.f;
        p0 = fmaf(v, w0[j], p0);
        p1 = fmaf(v, w1[j], p1);
      }
      #pragma unroll
      for (int m = 1; m < 16; m <<= 1) {
        p0 += __shfl_xor(p0, m);
        p1 += __shfl_xor(p1, m);
      }
      if ((lane & 15) == 0) {
        const int gpad = pad_base + crow0 + i * 16 + r;
        const int b = gpad / NPAD;
        const int rr = gpad - b * NPAD;
        if (rr < NCAND) {
          float* o = out + ((size_t)b * NCAND + rr) * 2;
          atomicAdd(o,     p0);
          atomicAdd(o + 1, p1);
        }
      }
    }
  }
}

// ---------------- launch ----------------
extern "C" void kernel_launch(void* const* d_in, const int* in_sizes, int n_in,
                              void* d_out, int out_size, void* d_ws, size_t ws_size,
                              hipStream_t stream)
{
  const float* doc = (const float*)d_in[0];
  const float* qe  = (const float*)d_in[1];
  const float* W1  = (const float*)d_in[2];
  const float* g1  = (const float*)d_in[3];
  const float* b1  = (const float*)d_in[4];
  const float* m1  = (const float*)d_in[5];
  const float* v1  = (const float*)d_in[6];
  const float* W2  = (const float*)d_in[7];
  const float* g2  = (const float*)d_in[8];
  const float* b2  = (const float*)d_in[9];
  const float* m2  = (const float*)d_in[10];
  const float* v2  = (const float*)d_in[11];
  const float* W3  = (const float*)d_in[12];
  float* out = (float*)d_out;

  char* ws = (char*)d_ws;
  size_t off = 0;
  auto alloc = [&](size_t bytes) -> void* {
    void* p = ws + off;
    off = (off + bytes + 255) & ~(size_t)255;
    return p;
  };
  float*          F     = (float*)alloc((size_t)BATCH * T_LEN * DD * 4);
  float*          R     = (float*)alloc((size_t)BATCH * T_LEN * DD * 4);
  float*          qfbuf = (float*)alloc((size_t)BATCH * EE * 4);
  unsigned short* W1b   = (unsigned short*)alloc((size_t)H1 * KP * 2);
  float*          bias1 = (float*)alloc((size_t)H1 * 4);
  unsigned short* W2b   = (unsigned short*)alloc((size_t)H2 * H1 * 2);
  float*          bias2 = (float*)alloc((size_t)H2 * 4);
  const size_t off_common = off;

  // fused path needs: X (MROWS_F x KP) + h1 (MROWS_F x H1), both bf16
  const size_t need_fused = off_common + ((size_t)MROWS_F * KP * 2 + 256)
                                       + ((size_t)MROWS_F * H1 * 2 + 256);

  // common prep
  k_scan<<<dim3(26, BATCH, 2), 320, 0, stream>>>(doc, F, R);
  k_qf<<<dim3(BATCH), 320, 0, stream>>>(qe, qfbuf);
  k_w1<<<dim3(19, H1), 64, 0, stream>>>(W1, g1, v1, W1b);
  k_w2<<<dim3(16, H2), 64, 0, stream>>>(W2, g2, v2, W2b);
  k_bias<<<dim3(6), 256, 0, stream>>>(g1, b1, m1, v1, g2, b2, m2, v2, bias1, bias2);
  k_zero_out<<<dim3((out_size + 255) / 256), 256, 0, stream>>>(out, out_size);

  if (ws_size >= need_fused) {
    unsigned short* X  = (unsigned short*)alloc((size_t)MROWS_F * KP * 2);
    unsigned short* h1 = (unsigned short*)alloc((size_t)MROWS_F * H1 * 2);
    k_build_x<<<dim3((MROWS_F * 304 + 255) / 256), 256, 0, stream>>>(F, R, qfbuf, X, MROWS_F, 0);
    k_gemm<<<dim3(H1 / 128, MT_F), 256, 0, stream>>>(X, W1b, bias1, h1, KP, H1);
    k_gemm2_out<<<dim3(H2 / 128, MT_F), 256, 0, stream>>>(h1, W2b, bias2, W3, out, H1, 0);
  } else {
    unsigned short* X  = (unsigned short*)alloc((size_t)NPAD * KP * 2);
    unsigned short* h1 = (unsigned short*)alloc((size_t)NPAD * H1 * 2);
    for (int b = 0; b < BATCH; ++b) {
      k_build_x<<<dim3((NPAD * 304 + 255) / 256), 256, 0, stream>>>(F, R, qfbuf, X, NPAD, b);
      k_gemm<<<dim3(H1 / 128, MT_1), 256, 0, stream>>>(X, W1b, bias1, h1, KP, H1);
      k_gemm2_out<<<dim3(H2 / 128, MT_1), 256, 0, stream>>>(h1, W2b, bias2, W3, out, H1, b * NPAD);
    }
  }
}

// Round 3
// 474.688 us; speedup vs baseline: 1.2682x; 1.0093x over previous
//
#include <hip/hip_runtime.h>
#include <string.h>

// ---------------- problem constants ----------------
#define T_LEN   809
#define DD      304
#define EE      300
#define LQ      30
#define NCAND   12824      // candidates per batch
#define NPAD    12928      // 101 * 128 (padded rows per batch)
#define KP      1216       // 1212 padded to mult of 32
#define CIN     1212
#define H1      1024
#define H2      512
#define BATCH   4
#define MROWS_F (BATCH * NPAD)          // 51712 fused rows
#define MT_F    (MROWS_F / 128)         // 404
#define MT_1    (NPAD / 128)            // 101

// alpha^(span+1), span in [0,16)
__device__ __constant__ float c_coef[16] = {
  0.9f, 0.81f, 0.729f, 0.6561f, 0.59049f, 0.531441f, 0.4782969f, 0.43046721f,
  0.387420489f, 0.3486784401f, 0.31381059609f, 0.282429536481f,
  0.2541865828329f, 0.22876792454961f, 0.205891132094649f, 0.1853020188851841f
};

__device__ __forceinline__ unsigned short f2bf(float f) {
  unsigned int u = __float_as_uint(f);
  u += 0x7fffu + ((u >> 16) & 1u);          // round-to-nearest-even
  return (unsigned short)(u >> 16);
}

typedef const __attribute__((address_space(1))) unsigned int GU32;
typedef __attribute__((address_space(3))) unsigned int LU32;
__device__ __forceinline__ void async16(const unsigned short* g, unsigned short* l) {
  __builtin_amdgcn_global_load_lds((GU32*)g, (LU32*)l, 16, 0, 0);
}

// ---------------- F / R decay scans (chunked, 192-step lookback) ----------------
__global__ __launch_bounds__(320) void k_scan(const float* __restrict__ doc,
                                              float* __restrict__ F,
                                              float* __restrict__ R)
{
  const int d  = threadIdx.x;
  if (d >= DD) return;
  const int t0 = blockIdx.x * 32;
  const int b  = blockIdx.y;
  const float* db = doc + (size_t)b * T_LEN * DD + d;
  if (blockIdx.z == 0) {
    int start = t0 - 192; if (start < 0) start = 0;
    int end = t0 + 31; if (end > T_LEN - 1) end = T_LEN - 1;
    float s = 0.f;
    for (int t = start; t <= end; ++t) {
      s = fmaf(0.9f, s, db[(size_t)t * DD]);
      if (t >= t0) F[((size_t)b * T_LEN + t) * DD + d] = s;
    }
  } else {
    int t1 = t0 + 31; if (t1 > T_LEN - 1) t1 = T_LEN - 1;
    int start = t1 + 192; if (start > T_LEN - 1) start = T_LEN - 1;
    float s = 0.f;
    for (int t = start; t >= t0; --t) {
      s = fmaf(0.9f, s, db[(size_t)t * DD]);
      if (t <= t1) R[((size_t)b * T_LEN + t) * DD + d] = s;
    }
  }
}

// ---------------- query FOFE ----------------
__global__ __launch_bounds__(320) void k_qf(const float* __restrict__ q, float* __restrict__ qf)
{
  const int d = threadIdx.x;
  const int b = blockIdx.x;
  if (d >= EE) return;
  float s = 0.f;
  for (int t = 0; t < LQ; ++t) s = fmaf(s, 0.9f, q[((size_t)b * LQ + t) * EE + d]);
  qf[b * EE + d] = s;
}

// ---------------- BN-folded weight prep (fp32 -> bf16) ----------------
__global__ __launch_bounds__(64) void k_w1(const float* __restrict__ W1, const float* __restrict__ g1,
                                           const float* __restrict__ v1, unsigned short* __restrict__ W1b)
{
  const int k = blockIdx.x * 64 + threadIdx.x;
  const int j = blockIdx.y;
  float w = 0.f;
  if (k < CIN) w = W1[(size_t)j * CIN + k] * g1[j] * rsqrtf(v1[j] + 1e-5f);
  W1b[(size_t)j * KP + k] = f2bf(w);
}
__global__ __launch_bounds__(64) void k_w2(const float* __restrict__ W2, const float* __restrict__ g2,
                                           const float* __restrict__ v2, unsigned short* __restrict__ W2b)
{
  const int k = blockIdx.x * 64 + threadIdx.x;
  const int j = blockIdx.y;
  float w = W2[(size_t)j * H1 + k] * g2[j] * rsqrtf(v2[j] + 1e-5f);
  W2b[(size_t)j * H1 + k] = f2bf(w);
}
__global__ __launch_bounds__(256) void k_bias(const float* g1, const float* b1, const float* m1, const float* v1,
                                              const float* g2, const float* b2, const float* m2, const float* v2,
                                              float* bias1, float* bias2)
{
  const int i = blockIdx.x * 256 + threadIdx.x;
  if (i < H1) {
    float s = g1[i] * rsqrtf(v1[i] + 1e-5f);
    bias1[i] = b1[i] - m1[i] * s;
  } else if (i < H1 + H2) {
    int j = i - H1;
    float s = g2[j] * rsqrtf(v2[j] + 1e-5f);
    bias2[j] = b2[j] - m2[j] * s;
  }
}

// ---------------- build X (bf16, row-major nrow x KP) ----------------
// k-layout: [0,304)=lctx  [304,608)=cand  [608,912)=rctx  [912,1212)=qf  [1212,1216)=0
__global__ __launch_bounds__(256) void k_build_x(const float* __restrict__ F, const float* __restrict__ R,
                                                 const float* __restrict__ qf, unsigned short* __restrict__ X,
                                                 int nrow, int b0)
{
  const int flat = blockIdx.x * 256 + threadIdx.x;
  if (flat >= nrow * 304) return;
  const int row = flat / 304;
  const int g = flat - row * 304;
  const int b = b0 + row / NPAD;
  const int r = row % NPAD;
  float v0 = 0.f, v1 = 0.f, v2 = 0.f, v3 = 0.f;
  if (r < NCAND) {
    int s, span;
    if (r < 12704) { s = r >> 4; span = r & 15; }
    else {
      int m = r - 12704; int j = 0, off = 0;
      while (off + (15 - j) <= m) { off += 15 - j; ++j; }
      s = 794 + j; span = m - off;
    }
    const int e = s + span;
    const float* Fb = F + (size_t)b * T_LEN * DD;
    const float* Rb = R + (size_t)b * T_LEN * DD;
    if (g < 76) {
      const int d = g * 4;
      if (s > 0) { float4 t = *(const float4*)(Fb + (size_t)(s - 1) * DD + d); v0=t.x; v1=t.y; v2=t.z; v3=t.w; }
    } else if (g < 152) {
      const int d = (g - 76) * 4;
      float4 fe = *(const float4*)(Fb + (size_t)e * DD + d);
      float4 fs = make_float4(0.f, 0.f, 0.f, 0.f);
      if (s > 0) fs = *(const float4*)(Fb + (size_t)(s - 1) * DD + d);
      const float c = c_coef[span];
      v0 = fe.x - c * fs.x; v1 = fe.y - c * fs.y; v2 = fe.z - c * fs.z; v3 = fe.w - c * fs.w;
    } else if (g < 228) {
      const int d = (g - 152) * 4;
      if (e + 1 < T_LEN) { float4 t = *(const float4*)(Rb + (size_t)(e + 1) * DD + d); v0=t.x; v1=t.y; v2=t.z; v3=t.w; }
    } else if (g < 303) {
      const int d = (g - 228) * 4;
      float4 t = *(const float4*)(qf + b * EE + d);
      v0 = t.x; v1 = t.y; v2 = t.z; v3 = t.w;
    }
  }
  ushort4 o;
  o.x = f2bf(v0); o.y = f2bf(v1); o.z = f2bf(v2); o.w = f2bf(v3);
  *(ushort4*)(X + (size_t)row * KP + g * 4) = o;
}

// ---------------- bf16 GEMM1: C = relu(A * Bw^T + bias) -> bf16 ----------------
typedef __attribute__((ext_vector_type(8))) short frag8;
typedef __attribute__((ext_vector_type(4))) float f32x4;

// 128x128 tile, BK=32, 4 waves of 64x64. swz=1: XCD-aware remap (requires grid 8 x 404):
// XCD = flat%8 gets a quarter of bm-space; 4 consecutive same-XCD blocks share one A-tile.
__global__ __launch_bounds__(256) void k_gemm(const unsigned short* __restrict__ A,
                                              const unsigned short* __restrict__ Bw,
                                              const float* __restrict__ bias,
                                              unsigned short* __restrict__ C,
                                              int K, int Nout, int swz)
{
  __shared__ __align__(16) unsigned short As[128 * 32];
  __shared__ __align__(16) unsigned short Bs[128 * 32];
  const int tid  = threadIdx.x;
  const int lane = tid & 63;
  const int wv   = tid >> 6;
  const int wm   = wv & 1, wn = wv >> 1;
  int bn, bm;
  if (swz) {
    const int flat = blockIdx.y * 8 + blockIdx.x;
    const int v = flat & 7, rest = flat >> 3;
    bm = (v & 3) * 101 + (rest >> 2);
    bn = (v >> 2) * 4 + (rest & 3);
  } else {
    bn = blockIdx.x; bm = blockIdx.y;
  }

  const int lr = lane >> 2;
  const int lc = lane & 3;
  const unsigned short* gA = A  + ((size_t)bm * 128 + wv * 32 + lr) * K + lc * 8;
  const unsigned short* gB = Bw + ((size_t)bn * 128 + wv * 32 + lr) * K + lc * 8;
  const size_t row16 = (size_t)16 * K;
  unsigned short* lA0 = &As[wv * 1024];
  unsigned short* lB0 = &Bs[wv * 1024];

  f32x4 acc[4][4];
  #pragma unroll
  for (int i = 0; i < 4; ++i)
    #pragma unroll
    for (int j = 0; j < 4; ++j) acc[i][j] = (f32x4){0.f, 0.f, 0.f, 0.f};

  const int aoff = (wm * 64 + (lane & 15)) * 32 + (lane >> 4) * 8;
  const int boff = (wn * 64 + (lane & 15)) * 32 + (lane >> 4) * 8;

  for (int kc = 0; kc < K; kc += 32) {
    __syncthreads();
    async16(gA + kc,         lA0);
    async16(gA + kc + row16, lA0 + 512);
    async16(gB + kc,         lB0);
    async16(gB + kc + row16, lB0 + 512);
    __syncthreads();
    frag8 a[4], b[4];
    #pragma unroll
    for (int i = 0; i < 4; ++i) a[i] = *(const frag8*)&As[aoff + i * 512];
    #pragma unroll
    for (int i = 0; i < 4; ++i) b[i] = *(const frag8*)&Bs[boff + i * 512];
    #pragma unroll
    for (int i = 0; i < 4; ++i)
      #pragma unroll
      for (int j = 0; j < 4; ++j)
        acc[i][j] = __builtin_amdgcn_mfma_f32_16x16x32_bf16(a[i], b[j], acc[i][j], 0, 0, 0);
  }

  const int crow0 = bm * 128 + wm * 64 + ((lane >> 4) << 2);
  const int ccol0 = bn * 128 + wn * 64 + (lane & 15);
  #pragma unroll
  for (int i = 0; i < 4; ++i) {
    #pragma unroll
    for (int j = 0; j < 4; ++j) {
      const int col = ccol0 + j * 16;
      const float bj = bias[col];
      #pragma unroll
      for (int r = 0; r < 4; ++r) {
        const int row = crow0 + i * 16 + r;
        float v = acc[i][j][r] + bj;
        v = v > 0.f ? v : 0.f;
        C[(size_t)row * Nout + col] = f2bf(v);
      }
    }
  }
}

// ---------------- GEMM2 + final layer, atomic-free ----------------
// grid = (#row-tiles). Block owns 128 rows; loops the 4 col-tiles of W2 internally,
// carrying p = relu(h2)*W3 partials in registers; LDS reduce; exclusive out store.
__global__ __launch_bounds__(256) void k_gemm2_out(const unsigned short* __restrict__ A,
                                                   const unsigned short* __restrict__ W2b,
                                                   const float* __restrict__ bias,
                                                   const float* __restrict__ W3,
                                                   float* __restrict__ out,
                                                   int pad_base)
{
  __shared__ __align__(16) unsigned short As[128 * 32];
  __shared__ __align__(16) unsigned short Bs[128 * 32];
  __shared__ float red[2][4][4][4][2];            // [wm][i][r][grp][{p0,p1}]
  const int tid  = threadIdx.x;
  const int lane = tid & 63;
  const int wv   = tid >> 6;
  const int wm   = wv & 1, wn = wv >> 1;
  const int bm   = blockIdx.x;

  const int lr = lane >> 2;
  const int lc = lane & 3;
  const unsigned short* gA = A + ((size_t)bm * 128 + wv * 32 + lr) * H1 + lc * 8;
  const size_t row16 = (size_t)16 * H1;
  unsigned short* lA0 = &As[wv * 1024];
  unsigned short* lB0 = &Bs[wv * 1024];
  const int aoff = (wm * 64 + (lane & 15)) * 32 + (lane >> 4) * 8;
  const int boff = (wn * 64 + (lane & 15)) * 32 + (lane >> 4) * 8;

  float p0[4][4], p1[4][4];
  #pragma unroll
  for (int i = 0; i < 4; ++i)
    #pragma unroll
    for (int r = 0; r < 4; ++r) { p0[i][r] = 0.f; p1[i][r] = 0.f; }

  for (int bnt = 0; bnt < 4; ++bnt) {
    const unsigned short* gB = W2b + ((size_t)bnt * 128 + wv * 32 + lr) * H1 + lc * 8;
    f32x4 acc[4][4];
    #pragma unroll
    for (int i = 0; i < 4; ++i)
      #pragma unroll
      for (int j = 0; j < 4; ++j) acc[i][j] = (f32x4){0.f, 0.f, 0.f, 0.f};

    for (int kc = 0; kc < H1; kc += 32) {
      __syncthreads();
      async16(gA + kc,         lA0);
      async16(gA + kc + row16, lA0 + 512);
      async16(gB + kc,         lB0);
      async16(gB + kc + row16, lB0 + 512);
      __syncthreads();
      frag8 a[4], b[4];
      #pragma unroll
      for (int i = 0; i < 4; ++i) a[i] = *(const frag8*)&As[aoff + i * 512];
      #pragma unroll
      for (int i = 0; i < 4; ++i) b[i] = *(const frag8*)&Bs[boff + i * 512];
      #pragma unroll
      for (int i = 0; i < 4; ++i)
        #pragma unroll
        for (int j = 0; j < 4; ++j)
          acc[i][j] = __builtin_amdgcn_mfma_f32_16x16x32_bf16(a[i], b[j], acc[i][j], 0, 0, 0);
    }

    // fold this col-tile into the W3 partials
    const int ccol0 = bnt * 128 + wn * 64 + (lane & 15);
    float bj[4], w0[4], w1[4];
    #pragma unroll
    for (int j = 0; j < 4; ++j) {
      const int col = ccol0 + j * 16;
      bj[j] = bias[col];
      w0[j] = W3[col];
      w1[j] = W3[H2 + col];
    }
    #pragma unroll
    for (int i = 0; i < 4; ++i)
      #pragma unroll
      for (int r = 0; r < 4; ++r) {
        #pragma unroll
        for (int j = 0; j < 4; ++j) {
          float v = acc[i][j][r] + bj[j];
          v = v > 0.f ? v : 0.f;
          p0[i][r] = fmaf(v, w0[j], p0[i][r]);
          p1[i][r] = fmaf(v, w1[j], p1[i][r]);
        }
      }
  }

  // reduce across the 16 col-lanes of each group
  #pragma unroll
  for (int i = 0; i < 4; ++i)
    #pragma unroll
    for (int r = 0; r < 4; ++r) {
      #pragma unroll
      for (int m = 1; m < 16; m <<= 1) {
        p0[i][r] += __shfl_xor(p0[i][r], m);
        p1[i][r] += __shfl_xor(p1[i][r], m);
      }
    }

  const int grp = lane >> 4;
  if (wn == 1 && (lane & 15) == 0) {
    #pragma unroll
    for (int i = 0; i < 4; ++i)
      #pragma unroll
      for (int r = 0; r < 4; ++r) {
        red[wm][i][r][grp][0] = p0[i][r];
        red[wm][i][r][grp][1] = p1[i][r];
      }
  }
  __syncthreads();
  if (wn == 0 && (lane & 15) == 0) {
    #pragma unroll
    for (int i = 0; i < 4; ++i)
      #pragma unroll
      for (int r = 0; r < 4; ++r) {
        const float q0 = p0[i][r] + red[wm][i][r][grp][0];
        const float q1 = p1[i][r] + red[wm][i][r][grp][1];
        const int gpad = pad_base + bm * 128 + wm * 64 + grp * 4 + i * 16 + r;
        const int b = gpad / NPAD;
        const int rr = gpad - b * NPAD;
        if (rr < NCAND) {
          float* o = out + ((size_t)b * NCAND + rr) * 2;
          o[0] = q0;
          o[1] = q1;
        }
      }
  }
}

// ---------------- launch ----------------
extern "C" void kernel_launch(void* const* d_in, const int* in_sizes, int n_in,
                              void* d_out, int out_size, void* d_ws, size_t ws_size,
                              hipStream_t stream)
{
  const float* doc = (const float*)d_in[0];
  const float* qe  = (const float*)d_in[1];
  const float* W1  = (const float*)d_in[2];
  const float* g1  = (const float*)d_in[3];
  const float* b1  = (const float*)d_in[4];
  const float* m1  = (const float*)d_in[5];
  const float* v1  = (const float*)d_in[6];
  const float* W2  = (const float*)d_in[7];
  const float* g2  = (const float*)d_in[8];
  const float* b2  = (const float*)d_in[9];
  const float* m2  = (const float*)d_in[10];
  const float* v2  = (const float*)d_in[11];
  const float* W3  = (const float*)d_in[12];
  float* out = (float*)d_out;

  char* ws = (char*)d_ws;
  size_t off = 0;
  auto alloc = [&](size_t bytes) -> void* {
    void* p = ws + off;
    off = (off + bytes + 255) & ~(size_t)255;
    return p;
  };
  float*          F     = (float*)alloc((size_t)BATCH * T_LEN * DD * 4);
  float*          R     = (float*)alloc((size_t)BATCH * T_LEN * DD * 4);
  float*          qfbuf = (float*)alloc((size_t)BATCH * EE * 4);
  unsigned short* W1b   = (unsigned short*)alloc((size_t)H1 * KP * 2);
  float*          bias1 = (float*)alloc((size_t)H1 * 4);
  unsigned short* W2b   = (unsigned short*)alloc((size_t)H2 * H1 * 2);
  float*          bias2 = (float*)alloc((size_t)H2 * 4);
  const size_t off_common = off;

  const size_t need_fused = off_common + ((size_t)MROWS_F * KP * 2 + 256)
                                       + ((size_t)MROWS_F * H1 * 2 + 256);

  // common prep
  k_scan<<<dim3(26, BATCH, 2), 320, 0, stream>>>(doc, F, R);
  k_qf<<<dim3(BATCH), 320, 0, stream>>>(qe, qfbuf);
  k_w1<<<dim3(19, H1), 64, 0, stream>>>(W1, g1, v1, W1b);
  k_w2<<<dim3(16, H2), 64, 0, stream>>>(W2, g2, v2, W2b);
  k_bias<<<dim3(6), 256, 0, stream>>>(g1, b1, m1, v1, g2, b2, m2, v2, bias1, bias2);

  if (ws_size >= need_fused) {
    unsigned short* X  = (unsigned short*)alloc((size_t)MROWS_F * KP * 2);
    unsigned short* h1 = (unsigned short*)alloc((size_t)MROWS_F * H1 * 2);
    k_build_x<<<dim3((MROWS_F * 304 + 255) / 256), 256, 0, stream>>>(F, R, qfbuf, X, MROWS_F, 0);
    k_gemm<<<dim3(H1 / 128, MT_F), 256, 0, stream>>>(X, W1b, bias1, h1, KP, H1, 1);
    k_gemm2_out<<<dim3(MT_F), 256, 0, stream>>>(h1, W2b, bias2, W3, out, 0);
  } else {
    unsigned short* X  = (unsigned short*)alloc((size_t)NPAD * KP * 2);
    unsigned short* h1 = (unsigned short*)alloc((size_t)NPAD * H1 * 2);
    for (int b = 0; b < BATCH; ++b) {
      k_build_x<<<dim3((NPAD * 304 + 255) / 256), 256, 0, stream>>>(F, R, qfbuf, X, NPAD, b);
      k_gemm<<<dim3(H1 / 128, MT_1), 256, 0, stream>>>(X, W1b, bias1, h1, KP, H1, 0);
      k_gemm2_out<<<dim3(MT_1), 256, 0, stream>>>(h1, W2b, bias2, W3, out, b * NPAD);
    }
  }
}

// Round 4
// 344.386 us; speedup vs baseline: 1.7480x; 1.3784x over previous
//
#include <hip/hip_runtime.h>
#include <string.h>

// ---------------- problem constants ----------------
#define T_LEN   809
#define DD      304
#define EE      300
#define LQ      30
#define NCAND   12824      // candidates per batch
#define NPAD    12928      // 101 * 128 (padded rows per batch)
#define CIN     1212
#define H1      1024
#define H2      512
#define BATCH   4
#define MROWS_F (BATCH * NPAD)          // 51712 fused rows
#define MT_F    (MROWS_F / 128)         // 404
#define KS      320                     // 304 padded to mult of 32 (scan-GEMM K)
#define TROWS   (BATCH * 810)           // 3240 table rows (incl. zero rows)
#define TPAD    3328                    // 26 * 128

// alpha^(span+1), span in [0,16)
__device__ __constant__ float c_coef[16] = {
  0.9f, 0.81f, 0.729f, 0.6561f, 0.59049f, 0.531441f, 0.4782969f, 0.43046721f,
  0.387420489f, 0.3486784401f, 0.31381059609f, 0.282429536481f,
  0.2541865828329f, 0.22876792454961f, 0.205891132094649f, 0.1853020188851841f
};

__device__ __forceinline__ unsigned short f2bf(float f) {
  unsigned int u = __float_as_uint(f);
  u += 0x7fffu + ((u >> 16) & 1u);          // round-to-nearest-even
  return (unsigned short)(u >> 16);
}

typedef const __attribute__((address_space(1))) unsigned int GU32;
typedef __attribute__((address_space(3))) unsigned int LU32;
__device__ __forceinline__ void async16(const unsigned short* g, unsigned short* l) {
  __builtin_amdgcn_global_load_lds((GU32*)g, (LU32*)l, 16, 0, 0);
}

// ---------------- F / R decay scans -> bf16 tables with zero guard rows ----------------
// Fz: per batch 810 rows (stride KS): row 0 = 0, row t = F[t-1].  Rz: row t = R[t] (t<809), row 809 = 0.
__global__ __launch_bounds__(320) void k_scan(const float* __restrict__ doc,
                                              unsigned short* __restrict__ Fz,
                                              unsigned short* __restrict__ Rz)
{
  const int d  = threadIdx.x;
  const int t0 = blockIdx.x * 32;
  const int b  = blockIdx.y;
  const float* db = doc + (size_t)b * T_LEN * DD + d;
  if (blockIdx.z == 0) {
    if (blockIdx.x == 0) Fz[((size_t)b * 810) * KS + d] = 0;   // zero row
    if (d >= DD) return;
    int start = t0 - 192; if (start < 0) start = 0;
    int end = t0 + 31; if (end > T_LEN - 1) end = T_LEN - 1;
    float s = 0.f;
    for (int t = start; t <= end; ++t) {
      s = fmaf(0.9f, s, db[(size_t)t * DD]);
      if (t >= t0) Fz[((size_t)b * 810 + 1 + t) * KS + d] = f2bf(s);
    }
  } else {
    if (blockIdx.x == 0) Rz[((size_t)b * 810 + 809) * KS + d] = 0;  // zero row
    if (d >= DD) return;
    int t1 = t0 + 31; if (t1 > T_LEN - 1) t1 = T_LEN - 1;
    int start = t1 + 192; if (start > T_LEN - 1) start = T_LEN - 1;
    float s = 0.f;
    for (int t = start; t >= t0; --t) {
      s = fmaf(0.9f, s, db[(size_t)t * DD]);
      if (t <= t1) Rz[((size_t)b * 810 + t) * KS + d] = f2bf(s);
    }
  }
}

// ---------------- query FOFE ----------------
__global__ __launch_bounds__(320) void k_qf(const float* __restrict__ q, float* __restrict__ qf)
{
  const int d = threadIdx.x;
  const int b = blockIdx.x;
  if (d >= EE) return;
  float s = 0.f;
  for (int t = 0; t < LQ; ++t) s = fmaf(s, 0.9f, q[((size_t)b * LQ + t) * EE + d]);
  qf[b * EE + d] = s;
}

// ---------------- BN-folded split weights (fp32 -> bf16) ----------------
// Wlc: 2048 x KS. rows [0,1024) = s_j*W1[j, 0:304] (lctx); rows [1024,2048) = s_j*W1[j-1024, 304:608] (cand)
__global__ __launch_bounds__(64) void k_wlc(const float* __restrict__ W1, const float* __restrict__ g1,
                                            const float* __restrict__ v1, unsigned short* __restrict__ Wlc)
{
  const int k = blockIdx.x * 64 + threadIdx.x;   // 0..319
  const int j = blockIdx.y;                      // 0..2047
  const int jj = j & 1023;
  const int koff = (j < 1024) ? k : 304 + k;
  float w = 0.f;
  if (k < 304) w = W1[(size_t)jj * CIN + koff] * g1[jj] * rsqrtf(v1[jj] + 1e-5f);
  Wlc[(size_t)j * KS + k] = f2bf(w);
}
// Wr: 1024 x KS = s_j*W1[j, 608:912]
__global__ __launch_bounds__(64) void k_wr(const float* __restrict__ W1, const float* __restrict__ g1,
                                           const float* __restrict__ v1, unsigned short* __restrict__ Wr)
{
  const int k = blockIdx.x * 64 + threadIdx.x;
  const int j = blockIdx.y;
  float w = 0.f;
  if (k < 304) w = W1[(size_t)j * CIN + 608 + k] * g1[j] * rsqrtf(v1[j] + 1e-5f);
  Wr[(size_t)j * KS + k] = f2bf(w);
}
__global__ __launch_bounds__(64) void k_w2(const float* __restrict__ W2, const float* __restrict__ g2,
                                           const float* __restrict__ v2, unsigned short* __restrict__ W2b)
{
  const int k = blockIdx.x * 64 + threadIdx.x;
  const int j = blockIdx.y;
  float w = W2[(size_t)j * H1 + k] * g2[j] * rsqrtf(v2[j] + 1e-5f);
  W2b[(size_t)j * H1 + k] = f2bf(w);
}
__global__ __launch_bounds__(256) void k_bias2(const float* __restrict__ g2, const float* __restrict__ b2,
                                               const float* __restrict__ m2, const float* __restrict__ v2,
                                               float* __restrict__ bias2)
{
  const int i = blockIdx.x * 256 + threadIdx.x;
  if (i < H2) {
    float s = g2[i] * rsqrtf(v2[i] + 1e-5f);
    bias2[i] = b2[i] - m2[i] * s;
  }
}

// ---------------- base[b][j] = bias1'[j] + qf[b] . (s_j * W1[j, 912:1212]) ----------------
__global__ __launch_bounds__(256) void k_base(const float* __restrict__ W1, const float* __restrict__ g1,
                                              const float* __restrict__ b1, const float* __restrict__ m1,
                                              const float* __restrict__ v1, const float* __restrict__ qf,
                                              float* __restrict__ base)
{
  const int b = blockIdx.x;
  const int j = blockIdx.y * 256 + threadIdx.x;   // 0..1023
  const float s = g1[j] * rsqrtf(v1[j] + 1e-5f);
  const float* w = W1 + (size_t)j * CIN + 912;
  const float* q = qf + b * EE;
  float acc = 0.f;
  for (int k = 0; k < EE; ++k) acc = fmaf(q[k], w[k], acc);
  base[b * H1 + j] = b1[j] - m1[j] * s + acc * s;
}

// ---------------- GEMM machinery ----------------
typedef __attribute__((ext_vector_type(8))) short frag8;
typedef __attribute__((ext_vector_type(4))) float f32x4;

// 128x128 tile, BK=32, 4 waves of 64x64.  Requires bm, bn, and declares everything else.
#define GEMM_KLOOP(A_, B_, K_)                                                   \
  __shared__ __align__(16) unsigned short As[128 * 32];                          \
  __shared__ __align__(16) unsigned short Bs[128 * 32];                          \
  const int tid  = threadIdx.x;                                                  \
  const int lane = tid & 63;                                                     \
  const int wv   = tid >> 6;                                                     \
  const int wm   = wv & 1, wn = wv >> 1;                                         \
  const int lr = lane >> 2;                                                      \
  const int lc = lane & 3;                                                       \
  const unsigned short* gA = A_ + ((size_t)bm * 128 + wv * 32 + lr) * K_ + lc * 8; \
  const unsigned short* gB = B_ + ((size_t)bn * 128 + wv * 32 + lr) * K_ + lc * 8; \
  const size_t row16 = (size_t)16 * K_;                                          \
  unsigned short* lA0 = &As[wv * 1024];                                          \
  unsigned short* lB0 = &Bs[wv * 1024];                                          \
  f32x4 acc[4][4];                                                               \
  _Pragma("unroll")                                                              \
  for (int i = 0; i < 4; ++i)                                                    \
    _Pragma("unroll")                                                            \
    for (int j = 0; j < 4; ++j) acc[i][j] = (f32x4){0.f, 0.f, 0.f, 0.f};         \
  const int aoff = (wm * 64 + (lane & 15)) * 32 + (lane >> 4) * 8;               \
  const int boff = (wn * 64 + (lane & 15)) * 32 + (lane >> 4) * 8;               \
  for (int kc = 0; kc < K_; kc += 32) {                                          \
    __syncthreads();                                                             \
    async16(gA + kc,         lA0);                                               \
    async16(gA + kc + row16, lA0 + 512);                                         \
    async16(gB + kc,         lB0);                                               \
    async16(gB + kc + row16, lB0 + 512);                                         \
    __syncthreads();                                                             \
    frag8 a[4], b[4];                                                            \
    _Pragma("unroll")                                                            \
    for (int i = 0; i < 4; ++i) a[i] = *(const frag8*)&As[aoff + i * 512];       \
    _Pragma("unroll")                                                            \
    for (int i = 0; i < 4; ++i) b[i] = *(const frag8*)&Bs[boff + i * 512];       \
    _Pragma("unroll")                                                            \
    for (int i = 0; i < 4; ++i)                                                  \
      _Pragma("unroll")                                                          \
      for (int j = 0; j < 4; ++j)                                                \
        acc[i][j] = __builtin_amdgcn_mfma_f32_16x16x32_bf16(a[i], b[j], acc[i][j], 0, 0, 0); \
  }

// plain fp32-output GEMM (U tables): C = A * Bw^T
__global__ __launch_bounds__(256) void k_gemm_f32(const unsigned short* __restrict__ A,
                                                  const unsigned short* __restrict__ Bw,
                                                  float* __restrict__ C,
                                                  int K, int Nout)
{
  const int bn = blockIdx.x, bm = blockIdx.y;
  GEMM_KLOOP(A, Bw, K)
  const int crow0 = bm * 128 + wm * 64 + ((lane >> 4) << 2);
  const int ccol0 = bn * 128 + wn * 64 + (lane & 15);
  #pragma unroll
  for (int i = 0; i < 4; ++i)
    #pragma unroll
    for (int j = 0; j < 4; ++j) {
      const int col = ccol0 + j * 16;
      #pragma unroll
      for (int r = 0; r < 4; ++r)
        C[(size_t)(crow0 + i * 16 + r) * Nout + col] = acc[i][j][r];
    }
}

// ---------------- combine: h1 = relu(U_l[s] + U_c[e+1] - coef*U_c[s] + U_r[e+1] + base) ----------------
// UF rows: (b*810 + t), 2048 wide (cols 0..1023 = lctx part, 1024..2047 = cand part). UR rows 1024 wide.
__global__ __launch_bounds__(256) void k_combine(const float* __restrict__ UF,
                                                 const float* __restrict__ UR,
                                                 const float* __restrict__ base,
                                                 unsigned short* __restrict__ h1)
{
  const int s = blockIdx.x;          // 0..808
  const int b = blockIdx.y;
  const int tid = threadIdx.x;       // float4 column index (1024/4)
  const size_t rs = (size_t)b * 810 + s;
  const float4 ul  = ((const float4*)UF)[rs * 512 + tid];
  const float4 ucs = ((const float4*)UF)[rs * 512 + 256 + tid];
  const float4 bs  = ((const float4*)base)[b * 256 + tid];
  const int nspan = min(16, T_LEN - s);
  int r0;
  if (s < 794) r0 = s * 16;
  else { const int d = s - 794; r0 = 12704 + 15 * d - (d * (d - 1)) / 2; }
  for (int span = 0; span < nspan; ++span) {
    const size_t re = rs + span + 1;
    const float4 uce = ((const float4*)UF)[re * 512 + 256 + tid];
    const float4 ur  = ((const float4*)UR)[re * 256 + tid];
    const float c = c_coef[span];
    float x0 = ul.x + uce.x - c * ucs.x + ur.x + bs.x;
    float x1 = ul.y + uce.y - c * ucs.y + ur.y + bs.y;
    float x2 = ul.z + uce.z - c * ucs.z + ur.z + bs.z;
    float x3 = ul.w + uce.w - c * ucs.w + ur.w + bs.w;
    x0 = x0 > 0.f ? x0 : 0.f;  x1 = x1 > 0.f ? x1 : 0.f;
    x2 = x2 > 0.f ? x2 : 0.f;  x3 = x3 > 0.f ? x3 : 0.f;
    ushort4 o; o.x = f2bf(x0); o.y = f2bf(x1); o.z = f2bf(x2); o.w = f2bf(x3);
    ((ushort4*)h1)[((size_t)b * NPAD + r0 + span) * 256 + tid] = o;
  }
}

// ---------------- GEMM2 + fused W3: per-(row, bn) partials, atomic-free ----------------
// grid (8, 202): flat XCD-swizzled over 404 bm x 4 bn.  P[row*8 + bn*2 + {0,1}].
__global__ __launch_bounds__(256) void k_gemm2p(const unsigned short* __restrict__ A,
                                                const unsigned short* __restrict__ W2b,
                                                const float* __restrict__ bias,
                                                const float* __restrict__ W3,
                                                float* __restrict__ P)
{
  const int global = blockIdx.x * 202 + blockIdx.y;   // xcd-contiguous bm range, bn fastest
  const int bm = global >> 2;
  const int bn = global & 3;
  __shared__ float red[2][4][4][4][2];                // [wm][i][r][grp][{p0,p1}]
  GEMM_KLOOP(A, W2b, H1)

  const int ccol0 = bn * 128 + wn * 64 + (lane & 15);
  float bj[4], w0[4], w1[4];
  #pragma unroll
  for (int j = 0; j < 4; ++j) {
    const int col = ccol0 + j * 16;
    bj[j] = bias[col];
    w0[j] = W3[col];
    w1[j] = W3[H2 + col];
  }
  float p0[4][4], p1[4][4];
  #pragma unroll
  for (int i = 0; i < 4; ++i)
    #pragma unroll
    for (int r = 0; r < 4; ++r) {
      float q0 = 0.f, q1 = 0.f;
      #pragma unroll
      for (int j = 0; j < 4; ++j) {
        float v = acc[i][j][r] + bj[j];
        v = v > 0.f ? v : 0.f;
        q0 = fmaf(v, w0[j], q0);
        q1 = fmaf(v, w1[j], q1);
      }
      #pragma unroll
      for (int m = 1; m < 16; m <<= 1) {
        q0 += __shfl_xor(q0, m);
        q1 += __shfl_xor(q1, m);
      }
      p0[i][r] = q0; p1[i][r] = q1;
    }

  const int grp = lane >> 4;
  if (wn == 1 && (lane & 15) == 0) {
    #pragma unroll
    for (int i = 0; i < 4; ++i)
      #pragma unroll
      for (int r = 0; r < 4; ++r) {
        red[wm][i][r][grp][0] = p0[i][r];
        red[wm][i][r][grp][1] = p1[i][r];
      }
  }
  __syncthreads();
  if (wn == 0 && (lane & 15) == 0) {
    #pragma unroll
    for (int i = 0; i < 4; ++i)
      #pragma unroll
      for (int r = 0; r < 4; ++r) {
        const size_t row = (size_t)bm * 128 + wm * 64 + grp * 4 + i * 16 + r;
        P[row * 8 + bn * 2 + 0] = p0[i][r] + red[wm][i][r][grp][0];
        P[row * 8 + bn * 2 + 1] = p1[i][r] + red[wm][i][r][grp][1];
      }
  }
}

// ---------------- final: sum 4 bn-partials per row -> out ----------------
__global__ __launch_bounds__(256) void k_fin(const float* __restrict__ P, float* __restrict__ out)
{
  const int row = blockIdx.x * 256 + threadIdx.x;
  if (row >= MROWS_F) return;
  const int b = row / NPAD;
  const int rr = row - b * NPAD;
  if (rr >= NCAND) return;
  const float4 pa = ((const float4*)P)[row * 2];
  const float4 pb = ((const float4*)P)[row * 2 + 1];
  float* o = out + ((size_t)b * NCAND + rr) * 2;
  o[0] = pa.x + pa.z + pb.x + pb.z;
  o[1] = pa.y + pa.w + pb.y + pb.w;
}

// ---------------- launch ----------------
extern "C" void kernel_launch(void* const* d_in, const int* in_sizes, int n_in,
                              void* d_out, int out_size, void* d_ws, size_t ws_size,
                              hipStream_t stream)
{
  const float* doc = (const float*)d_in[0];
  const float* qe  = (const float*)d_in[1];
  const float* W1  = (const float*)d_in[2];
  const float* g1  = (const float*)d_in[3];
  const float* b1  = (const float*)d_in[4];
  const float* m1  = (const float*)d_in[5];
  const float* v1  = (const float*)d_in[6];
  const float* W2  = (const float*)d_in[7];
  const float* g2  = (const float*)d_in[8];
  const float* b2  = (const float*)d_in[9];
  const float* m2  = (const float*)d_in[10];
  const float* v2  = (const float*)d_in[11];
  const float* W3  = (const float*)d_in[12];
  float* out = (float*)d_out;

  char* ws = (char*)d_ws;
  size_t off = 0;
  auto alloc = [&](size_t bytes) -> void* {
    void* p = ws + off;
    off = (off + bytes + 255) & ~(size_t)255;
    return p;
  };
  unsigned short* Fz    = (unsigned short*)alloc((size_t)TPAD * KS * 2);
  unsigned short* Rz    = (unsigned short*)alloc((size_t)TPAD * KS * 2);
  float*          qfbuf = (float*)alloc((size_t)BATCH * EE * 4);
  unsigned short* Wlc   = (unsigned short*)alloc((size_t)2048 * KS * 2);
  unsigned short* Wr    = (unsigned short*)alloc((size_t)1024 * KS * 2);
  unsigned short* W2b   = (unsigned short*)alloc((size_t)H2 * H1 * 2);
  float*          bias2 = (float*)alloc((size_t)H2 * 4);
  float*          base  = (float*)alloc((size_t)BATCH * H1 * 4);
  float*          UF    = (float*)alloc((size_t)TPAD * 2048 * 4);
  float*          UR    = (float*)alloc((size_t)TPAD * 1024 * 4);
  unsigned short* h1    = (unsigned short*)alloc((size_t)MROWS_F * H1 * 2);
  float*          P     = (float*)alloc((size_t)MROWS_F * 8 * 4);
  (void)ws_size;

  // prep
  k_scan<<<dim3(26, BATCH, 2), 320, 0, stream>>>(doc, Fz, Rz);
  k_qf<<<dim3(BATCH), 320, 0, stream>>>(qe, qfbuf);
  k_wlc<<<dim3(5, 2048), 64, 0, stream>>>(W1, g1, v1, Wlc);
  k_wr<<<dim3(5, 1024), 64, 0, stream>>>(W1, g1, v1, Wr);
  k_w2<<<dim3(16, H2), 64, 0, stream>>>(W2, g2, v2, W2b);
  k_bias2<<<dim3(2), 256, 0, stream>>>(g2, b2, m2, v2, bias2);
  k_base<<<dim3(BATCH, 4), 256, 0, stream>>>(W1, g1, b1, m1, v1, qfbuf, base);

  // tiny GEMMs: U tables (fp32)
  k_gemm_f32<<<dim3(16, TPAD / 128), 256, 0, stream>>>(Fz, Wlc, UF, KS, 2048);
  k_gemm_f32<<<dim3(8, TPAD / 128), 256, 0, stream>>>(Rz, Wr, UR, KS, 1024);

  // gather-combine -> h1 (bf16)
  k_combine<<<dim3(T_LEN, BATCH), 256, 0, stream>>>(UF, UR, base, h1);

  // GEMM2 with fused W3 partials, then reduce
  k_gemm2p<<<dim3(8, 202), 256, 0, stream>>>(h1, W2b, bias2, W3, P);
  k_fin<<<dim3((MROWS_F + 255) / 256), 256, 0, stream>>>(P, out);
}

// Round 5
// 323.864 us; speedup vs baseline: 1.8587x; 1.0634x over previous
//
#include <hip/hip_runtime.h>
#include <string.h>

// ---------------- problem constants ----------------
#define T_LEN   809
#define DD      304
#define EE      300
#define LQ      30
#define NCAND   12824      // candidates per batch
#define NPAD    12928      // 101 * 128 (padded rows per batch)
#define CIN     1212
#define H1      1024
#define H2      512
#define BATCH   4
#define MROWS_F (BATCH * NPAD)          // 51712 fused rows
#define MT_F    (MROWS_F / 128)         // 404
#define KS      320                     // 304 padded to mult of 32 (scan-GEMM K)
#define TPAD    3328                    // 26 * 128

// alpha^(span+1), span in [0,16)
__device__ __constant__ float c_coef[16] = {
  0.9f, 0.81f, 0.729f, 0.6561f, 0.59049f, 0.531441f, 0.4782969f, 0.43046721f,
  0.387420489f, 0.3486784401f, 0.31381059609f, 0.282429536481f,
  0.2541865828329f, 0.22876792454961f, 0.205891132094649f, 0.1853020188851841f
};

__device__ __forceinline__ unsigned short f2bf(float f) {
  unsigned int u = __float_as_uint(f);
  u += 0x7fffu + ((u >> 16) & 1u);          // round-to-nearest-even
  return (unsigned short)(u >> 16);
}
__device__ __forceinline__ float bf2f(unsigned int h) {
  return __uint_as_float(h << 16);
}

typedef const __attribute__((address_space(1))) unsigned int GU32;
typedef __attribute__((address_space(3))) unsigned int LU32;
__device__ __forceinline__ void async16(const unsigned short* g, unsigned short* l) {
  __builtin_amdgcn_global_load_lds((GU32*)g, (LU32*)l, 16, 0, 0);
}

// ---------------- F / R decay scans -> bf16 tables with zero guard rows ----------------
// Fz: per batch 810 rows (stride KS): row 0 = 0, row 1+t = F[t].  Rz: row t = R[t], row 809 = 0.
__global__ __launch_bounds__(320) void k_scan(const float* __restrict__ doc,
                                              unsigned short* __restrict__ Fz,
                                              unsigned short* __restrict__ Rz)
{
  const int d  = threadIdx.x;
  const int t0 = blockIdx.x * 32;
  const int b  = blockIdx.y;
  const float* db = doc + (size_t)b * T_LEN * DD + d;
  if (blockIdx.z == 0) {
    if (blockIdx.x == 0) Fz[((size_t)b * 810) * KS + d] = 0;   // zero row
    if (d >= DD) return;
    int start = t0 - 192; if (start < 0) start = 0;
    int end = t0 + 31; if (end > T_LEN - 1) end = T_LEN - 1;
    float s = 0.f;
    for (int t = start; t <= end; ++t) {
      s = fmaf(0.9f, s, db[(size_t)t * DD]);
      if (t >= t0) Fz[((size_t)b * 810 + 1 + t) * KS + d] = f2bf(s);
    }
  } else {
    if (blockIdx.x == 0) Rz[((size_t)b * 810 + 809) * KS + d] = 0;  // zero row
    if (d >= DD) return;
    int t1 = t0 + 31; if (t1 > T_LEN - 1) t1 = T_LEN - 1;
    int start = t1 + 192; if (start > T_LEN - 1) start = T_LEN - 1;
    float s = 0.f;
    for (int t = start; t >= t0; --t) {
      s = fmaf(0.9f, s, db[(size_t)t * DD]);
      if (t <= t1) Rz[((size_t)b * 810 + t) * KS + d] = f2bf(s);
    }
  }
}

// ---------------- query FOFE ----------------
__global__ __launch_bounds__(320) void k_qf(const float* __restrict__ q, float* __restrict__ qf)
{
  const int d = threadIdx.x;
  const int b = blockIdx.x;
  if (d >= EE) return;
  float s = 0.f;
  for (int t = 0; t < LQ; ++t) s = fmaf(s, 0.9f, q[((size_t)b * LQ + t) * EE + d]);
  qf[b * EE + d] = s;
}

// ---------------- BN-folded split weights (fp32 -> bf16), one kernel ----------------
// j in [0,1024): Wlc lctx rows; [1024,2048): Wlc cand rows; [2048,3072): Wr rows.
__global__ __launch_bounds__(64) void k_w1split(const float* __restrict__ W1, const float* __restrict__ g1,
                                                const float* __restrict__ v1,
                                                unsigned short* __restrict__ Wlc,
                                                unsigned short* __restrict__ Wr)
{
  const int k = blockIdx.x * 64 + threadIdx.x;   // 0..319
  const int j = blockIdx.y;                      // 0..3071
  int jj, koff; unsigned short* dst; size_t idx;
  if (j < 1024)      { jj = j;        koff = k;       dst = Wlc; idx = (size_t)j * KS + k; }
  else if (j < 2048) { jj = j - 1024; koff = 304 + k; dst = Wlc; idx = (size_t)j * KS + k; }
  else               { jj = j - 2048; koff = 608 + k; dst = Wr;  idx = (size_t)(j - 2048) * KS + k; }
  float w = 0.f;
  if (k < 304) w = W1[(size_t)jj * CIN + koff] * g1[jj] * rsqrtf(v1[jj] + 1e-5f);
  dst[idx] = f2bf(w);
}
__global__ __launch_bounds__(64) void k_w2(const float* __restrict__ W2, const float* __restrict__ g2,
                                           const float* __restrict__ v2, unsigned short* __restrict__ W2b)
{
  const int k = blockIdx.x * 64 + threadIdx.x;
  const int j = blockIdx.y;
  float w = W2[(size_t)j * H1 + k] * g2[j] * rsqrtf(v2[j] + 1e-5f);
  W2b[(size_t)j * H1 + k] = f2bf(w);
}
__global__ __launch_bounds__(256) void k_bias2(const float* __restrict__ g2, const float* __restrict__ b2,
                                               const float* __restrict__ m2, const float* __restrict__ v2,
                                               float* __restrict__ bias2)
{
  const int i = blockIdx.x * 256 + threadIdx.x;
  if (i < H2) {
    float s = g2[i] * rsqrtf(v2[i] + 1e-5f);
    bias2[i] = b2[i] - m2[i] * s;
  }
}

// ---------------- base[b][j] = bias1'[j] + qf[b] . (s_j * W1[j, 912:1212]) ----------------
// one wave per (b, j): coalesced reads + shuffle reduce
__global__ __launch_bounds__(256) void k_base(const float* __restrict__ W1, const float* __restrict__ g1,
                                              const float* __restrict__ b1, const float* __restrict__ m1,
                                              const float* __restrict__ v1, const float* __restrict__ qf,
                                              float* __restrict__ base)
{
  const int b = blockIdx.x;
  const int wv = threadIdx.x >> 6;
  const int lane = threadIdx.x & 63;
  const int j = blockIdx.y * 4 + wv;              // 0..1023
  const float* w = W1 + (size_t)j * CIN + 912;
  const float* q = qf + b * EE;
  float acc = 0.f;
  for (int k = lane; k < EE; k += 64) acc = fmaf(q[k], w[k], acc);
  #pragma unroll
  for (int off = 32; off; off >>= 1) acc += __shfl_down(acc, off);
  if (lane == 0) {
    const float sc = g1[j] * rsqrtf(v1[j] + 1e-5f);
    base[b * H1 + j] = b1[j] - m1[j] * sc + acc * sc;
  }
}

// ---------------- GEMM machinery ----------------
typedef __attribute__((ext_vector_type(8))) short frag8;
typedef __attribute__((ext_vector_type(4))) float f32x4;

// 128x128 tile, BK=32, 4 waves of 64x64 (for the small K=320 U-GEMMs)
#define GEMM_KLOOP(A_, B_, K_)                                                   \
  __shared__ __align__(16) unsigned short As[128 * 32];                          \
  __shared__ __align__(16) unsigned short Bs[128 * 32];                          \
  const int tid  = threadIdx.x;                                                  \
  const int lane = tid & 63;                                                     \
  const int wv   = tid >> 6;                                                     \
  const int wm   = wv & 1, wn = wv >> 1;                                         \
  const int lr = lane >> 2;                                                      \
  const int lc = lane & 3;                                                       \
  const unsigned short* gA = A_ + ((size_t)bm * 128 + wv * 32 + lr) * K_ + lc * 8; \
  const unsigned short* gB = B_ + ((size_t)bn * 128 + wv * 32 + lr) * K_ + lc * 8; \
  const size_t row16 = (size_t)16 * K_;                                          \
  unsigned short* lA0 = &As[wv * 1024];                                          \
  unsigned short* lB0 = &Bs[wv * 1024];                                          \
  f32x4 acc[4][4];                                                               \
  _Pragma("unroll")                                                              \
  for (int i = 0; i < 4; ++i)                                                    \
    _Pragma("unroll")                                                            \
    for (int j = 0; j < 4; ++j) acc[i][j] = (f32x4){0.f, 0.f, 0.f, 0.f};         \
  const int aoff = (wm * 64 + (lane & 15)) * 32 + (lane >> 4) * 8;               \
  const int boff = (wn * 64 + (lane & 15)) * 32 + (lane >> 4) * 8;               \
  for (int kc = 0; kc < K_; kc += 32) {                                          \
    __syncthreads();                                                             \
    async16(gA + kc,         lA0);                                               \
    async16(gA + kc + row16, lA0 + 512);                                         \
    async16(gB + kc,         lB0);                                               \
    async16(gB + kc + row16, lB0 + 512);                                         \
    __syncthreads();                                                             \
    frag8 a[4], b[4];                                                            \
    _Pragma("unroll")                                                            \
    for (int i = 0; i < 4; ++i) a[i] = *(const frag8*)&As[aoff + i * 512];       \
    _Pragma("unroll")                                                            \
    for (int i = 0; i < 4; ++i) b[i] = *(const frag8*)&Bs[boff + i * 512];       \
    _Pragma("unroll")                                                            \
    for (int i = 0; i < 4; ++i)                                                  \
      _Pragma("unroll")                                                          \
      for (int j = 0; j < 4; ++j)                                                \
        acc[i][j] = __builtin_amdgcn_mfma_f32_16x16x32_bf16(a[i], b[j], acc[i][j], 0, 0, 0); \
  }

// U-table GEMM, bf16 output: C = A * Bw^T
__global__ __launch_bounds__(256) void k_gemm_bf(const unsigned short* __restrict__ A,
                                                 const unsigned short* __restrict__ Bw,
                                                 unsigned short* __restrict__ C,
                                                 int K, int Nout)
{
  const int bn = blockIdx.x, bm = blockIdx.y;
  GEMM_KLOOP(A, Bw, K)
  const int crow0 = bm * 128 + wm * 64 + ((lane >> 4) << 2);
  const int ccol0 = bn * 128 + wn * 64 + (lane & 15);
  #pragma unroll
  for (int i = 0; i < 4; ++i)
    #pragma unroll
    for (int j = 0; j < 4; ++j) {
      const int col = ccol0 + j * 16;
      #pragma unroll
      for (int r = 0; r < 4; ++r)
        C[(size_t)(crow0 + i * 16 + r) * Nout + col] = f2bf(acc[i][j][r]);
    }
}

// ---------------- combine: h1 = relu(U_l[s] + U_c[e+1] - coef*U_c[s] + U_r[e+1] + base) ----------------
// UF rows (b*810+t), 2048 bf16 wide (0..1023 lctx, 1024..2047 cand). UR rows 1024 bf16.
__global__ __launch_bounds__(256) void k_combine(const unsigned short* __restrict__ UF,
                                                 const unsigned short* __restrict__ UR,
                                                 const float* __restrict__ base,
                                                 unsigned short* __restrict__ h1)
{
  const int s = blockIdx.x;            // 0..808
  const int b = blockIdx.y;
  const int half = threadIdx.x >> 7;   // 0/1: two span-rows in flight
  const int t = threadIdx.x & 127;     // 8-col group
  const size_t rs = (size_t)b * 810 + s;

  const uint4 ulp  = *(const uint4*)(UF + rs * 2048 + t * 8);
  const uint4 ucsp = *(const uint4*)(UF + rs * 2048 + 1024 + t * 8);
  const float4 b0 = *(const float4*)(base + b * H1 + t * 8);
  const float4 b1v = *(const float4*)(base + b * H1 + t * 8 + 4);
  float ul[8], ucs[8], bs[8];
  { const unsigned int* u = (const unsigned int*)&ulp;
    #pragma unroll
    for (int i = 0; i < 4; ++i) { ul[2*i] = bf2f(u[i] & 0xffff); ul[2*i+1] = bf2f(u[i] >> 16); } }
  { const unsigned int* u = (const unsigned int*)&ucsp;
    #pragma unroll
    for (int i = 0; i < 4; ++i) { ucs[2*i] = bf2f(u[i] & 0xffff); ucs[2*i+1] = bf2f(u[i] >> 16); } }
  bs[0]=b0.x; bs[1]=b0.y; bs[2]=b0.z; bs[3]=b0.w; bs[4]=b1v.x; bs[5]=b1v.y; bs[6]=b1v.z; bs[7]=b1v.w;

  const int nspan = min(16, T_LEN - s);
  int r0;
  if (s < 794) r0 = s * 16;
  else { const int d = s - 794; r0 = 12704 + 15 * d - (d * (d - 1)) / 2; }

  for (int sp = 0; sp < nspan; sp += 2) {
    const int row = sp + half;
    if (row < nspan) {
      const size_t re = rs + row + 1;
      const uint4 ucep = *(const uint4*)(UF + re * 2048 + 1024 + t * 8);
      const uint4 urp  = *(const uint4*)(UR + re * 1024 + t * 8);
      const float c = c_coef[row];
      const unsigned int* ue = (const unsigned int*)&ucep;
      const unsigned int* ur = (const unsigned int*)&urp;
      unsigned int o[4];
      #pragma unroll
      for (int i = 0; i < 4; ++i) {
        float xlo = ul[2*i]   + bf2f(ue[i] & 0xffff) - c * ucs[2*i]   + bf2f(ur[i] & 0xffff) + bs[2*i];
        float xhi = ul[2*i+1] + bf2f(ue[i] >> 16)    - c * ucs[2*i+1] + bf2f(ur[i] >> 16)    + bs[2*i+1];
        xlo = xlo > 0.f ? xlo : 0.f;
        xhi = xhi > 0.f ? xhi : 0.f;
        o[i] = (unsigned int)f2bf(xlo) | ((unsigned int)f2bf(xhi) << 16);
      }
      *(uint4*)(h1 + ((size_t)b * NPAD + r0 + row) * H1 + t * 8) = *(const uint4*)o;
    }
  }
}

// ---------------- GEMM2 + fused W3: BK=64, per-(row,bn) partials, atomic-free ----------------
__global__ __launch_bounds__(256) void k_gemm2p(const unsigned short* __restrict__ A,
                                                const unsigned short* __restrict__ W2b,
                                                const float* __restrict__ bias,
                                                const float* __restrict__ W3,
                                                float* __restrict__ P)
{
  const int global = blockIdx.x * 202 + blockIdx.y;   // xcd-contiguous bm range, bn fastest
  const int bm = global >> 2;
  const int bn = global & 3;
  __shared__ __align__(16) unsigned short As[128 * 64];
  __shared__ __align__(16) unsigned short Bs[128 * 64];
  __shared__ float red[2][4][4][4][2];                // [wm][i][r][grp][{p0,p1}]
  const int tid  = threadIdx.x;
  const int lane = tid & 63;
  const int wv   = tid >> 6;
  const int wm   = wv & 1, wn = wv >> 1;
  const int lr = lane >> 3;            // 0..7 row in 8-row issue group
  const int lc = lane & 7;             // 0..7 16B chunk in 128B row
  const unsigned short* gA = A   + ((size_t)bm * 128 + wv * 32 + lr) * H1 + lc * 8;
  const unsigned short* gB = W2b + ((size_t)bn * 128 + wv * 32 + lr) * H1 + lc * 8;
  unsigned short* lA0 = &As[wv * 32 * 64];
  unsigned short* lB0 = &Bs[wv * 32 * 64];

  f32x4 acc[4][4];
  #pragma unroll
  for (int i = 0; i < 4; ++i)
    #pragma unroll
    for (int j = 0; j < 4; ++j) acc[i][j] = (f32x4){0.f, 0.f, 0.f, 0.f};

  const int aoff = (wm * 64 + (lane & 15)) * 64 + (lane >> 4) * 8;
  const int boff = (wn * 64 + (lane & 15)) * 64 + (lane >> 4) * 8;

  for (int kc = 0; kc < H1; kc += 64) {
    __syncthreads();
    #pragma unroll
    for (int j = 0; j < 4; ++j) {
      async16(gA + kc + (size_t)j * 8 * H1, lA0 + j * 512);
      async16(gB + kc + (size_t)j * 8 * H1, lB0 + j * 512);
    }
    __syncthreads();
    #pragma unroll
    for (int ks = 0; ks < 2; ++ks) {
      frag8 a[4], b[4];
      #pragma unroll
      for (int i = 0; i < 4; ++i) a[i] = *(const frag8*)&As[aoff + ks * 32 + i * 1024];
      #pragma unroll
      for (int i = 0; i < 4; ++i) b[i] = *(const frag8*)&Bs[boff + ks * 32 + i * 1024];
      #pragma unroll
      for (int i = 0; i < 4; ++i)
        #pragma unroll
        for (int j = 0; j < 4; ++j)
          acc[i][j] = __builtin_amdgcn_mfma_f32_16x16x32_bf16(a[i], b[j], acc[i][j], 0, 0, 0);
    }
  }

  const int ccol0 = bn * 128 + wn * 64 + (lane & 15);
  float bj[4], w0[4], w1[4];
  #pragma unroll
  for (int j = 0; j < 4; ++j) {
    const int col = ccol0 + j * 16;
    bj[j] = bias[col];
    w0[j] = W3[col];
    w1[j] = W3[H2 + col];
  }
  float p0[4][4], p1[4][4];
  #pragma unroll
  for (int i = 0; i < 4; ++i)
    #pragma unroll
    for (int r = 0; r < 4; ++r) {
      float q0 = 0.f, q1 = 0.f;
      #pragma unroll
      for (int j = 0; j < 4; ++j) {
        float v = acc[i][j][r] + bj[j];
        v = v > 0.f ? v : 0.f;
        q0 = fmaf(v, w0[j], q0);
        q1 = fmaf(v, w1[j], q1);
      }
      #pragma unroll
      for (int m = 1; m < 16; m <<= 1) {
        q0 += __shfl_xor(q0, m);
        q1 += __shfl_xor(q1, m);
      }
      p0[i][r] = q0; p1[i][r] = q1;
    }

  const int grp = lane >> 4;
  if (wn == 1 && (lane & 15) == 0) {
    #pragma unroll
    for (int i = 0; i < 4; ++i)
      #pragma unroll
      for (int r = 0; r < 4; ++r) {
        red[wm][i][r][grp][0] = p0[i][r];
        red[wm][i][r][grp][1] = p1[i][r];
      }
  }
  __syncthreads();
  if (wn == 0 && (lane & 15) == 0) {
    #pragma unroll
    for (int i = 0; i < 4; ++i)
      #pragma unroll
      for (int r = 0; r < 4; ++r) {
        const size_t row = (size_t)bm * 128 + wm * 64 + grp * 4 + i * 16 + r;
        P[row * 8 + bn * 2 + 0] = p0[i][r] + red[wm][i][r][grp][0];
        P[row * 8 + bn * 2 + 1] = p1[i][r] + red[wm][i][r][grp][1];
      }
  }
}

// ---------------- final: sum 4 bn-partials per row -> out ----------------
__global__ __launch_bounds__(256) void k_fin(const float* __restrict__ P, float* __restrict__ out)
{
  const int row = blockIdx.x * 256 + threadIdx.x;
  if (row >= MROWS_F) return;
  const int b = row / NPAD;
  const int rr = row - b * NPAD;
  if (rr >= NCAND) return;
  const float4 pa = ((const float4*)P)[row * 2];
  const float4 pb = ((const float4*)P)[row * 2 + 1];
  float* o = out + ((size_t)b * NCAND + rr) * 2;
  o[0] = pa.x + pa.z + pb.x + pb.z;
  o[1] = pa.y + pa.w + pb.y + pb.w;
}

// ---------------- launch ----------------
extern "C" void kernel_launch(void* const* d_in, const int* in_sizes, int n_in,
                              void* d_out, int out_size, void* d_ws, size_t ws_size,
                              hipStream_t stream)
{
  const float* doc = (const float*)d_in[0];
  const float* qe  = (const float*)d_in[1];
  const float* W1  = (const float*)d_in[2];
  const float* g1  = (const float*)d_in[3];
  const float* b1  = (const float*)d_in[4];
  const float* m1  = (const float*)d_in[5];
  const float* v1  = (const float*)d_in[6];
  const float* W2  = (const float*)d_in[7];
  const float* g2  = (const float*)d_in[8];
  const float* b2  = (const float*)d_in[9];
  const float* m2  = (const float*)d_in[10];
  const float* v2  = (const float*)d_in[11];
  const float* W3  = (const float*)d_in[12];
  float* out = (float*)d_out;

  char* ws = (char*)d_ws;
  size_t off = 0;
  auto alloc = [&](size_t bytes) -> void* {
    void* p = ws + off;
    off = (off + bytes + 255) & ~(size_t)255;
    return p;
  };
  unsigned short* Fz    = (unsigned short*)alloc((size_t)TPAD * KS * 2);
  unsigned short* Rz    = (unsigned short*)alloc((size_t)TPAD * KS * 2);
  float*          qfbuf = (float*)alloc((size_t)BATCH * EE * 4);
  unsigned short* Wlc   = (unsigned short*)alloc((size_t)2048 * KS * 2);
  unsigned short* Wr    = (unsigned short*)alloc((size_t)1024 * KS * 2);
  unsigned short* W2b   = (unsigned short*)alloc((size_t)H2 * H1 * 2);
  float*          bias2 = (float*)alloc((size_t)H2 * 4);
  float*          base  = (float*)alloc((size_t)BATCH * H1 * 4);
  unsigned short* UF    = (unsigned short*)alloc((size_t)TPAD * 2048 * 2);
  unsigned short* UR    = (unsigned short*)alloc((size_t)TPAD * 1024 * 2);
  unsigned short* h1    = (unsigned short*)alloc((size_t)MROWS_F * H1 * 2);
  float*          P     = (float*)alloc((size_t)MROWS_F * 8 * 4);
  (void)ws_size;

  // prep
  k_scan<<<dim3(26, BATCH, 2), 320, 0, stream>>>(doc, Fz, Rz);
  k_qf<<<dim3(BATCH), 320, 0, stream>>>(qe, qfbuf);
  k_w1split<<<dim3(5, 3072), 64, 0, stream>>>(W1, g1, v1, Wlc, Wr);
  k_w2<<<dim3(16, H2), 64, 0, stream>>>(W2, g2, v2, W2b);
  k_bias2<<<dim3(2), 256, 0, stream>>>(g2, b2, m2, v2, bias2);
  k_base<<<dim3(BATCH, 256), 256, 0, stream>>>(W1, g1, b1, m1, v1, qfbuf, base);

  // U tables (bf16)
  k_gemm_bf<<<dim3(16, TPAD / 128), 256, 0, stream>>>(Fz, Wlc, UF, KS, 2048);
  k_gemm_bf<<<dim3(8, TPAD / 128), 256, 0, stream>>>(Rz, Wr, UR, KS, 1024);

  // gather-combine -> h1 (bf16)
  k_combine<<<dim3(T_LEN, BATCH), 256, 0, stream>>>(UF, UR, base, h1);

  // GEMM2 with fused W3 partials, then reduce
  k_gemm2p<<<dim3(8, 202), 256, 0, stream>>>(h1, W2b, bias2, W3, P);
  k_fin<<<dim3((MROWS_F + 255) / 256), 256, 0, stream>>>(P, out);
}

// Round 6
// 277.170 us; speedup vs baseline: 2.1719x; 1.1685x over previous
//
#include <hip/hip_runtime.h>
#include <string.h>

// ---------------- problem constants ----------------
#define T_LEN   809
#define DD      304
#define EE      300
#define LQ      30
#define NCAND   12824      // candidates per batch
#define NPAD    12928      // 101 * 128 (padded rows per batch)
#define CIN     1212
#define H1      1024
#define H2      512
#define BATCH   4
#define MROWS_F (BATCH * NPAD)          // 51712 fused rows
#define MT_F    (MROWS_F / 128)         // 404
#define KS      320                     // 304 padded to mult of 32 (scan-GEMM K)
#define TPAD    3328                    // 26 * 128

// alpha^(span+1), span in [0,16)
__device__ __constant__ float c_coef[16] = {
  0.9f, 0.81f, 0.729f, 0.6561f, 0.59049f, 0.531441f, 0.4782969f, 0.43046721f,
  0.387420489f, 0.3486784401f, 0.31381059609f, 0.282429536481f,
  0.2541865828329f, 0.22876792454961f, 0.205891132094649f, 0.1853020188851841f
};

__device__ __forceinline__ unsigned short f2bf(float f) {
  unsigned int u = __float_as_uint(f);
  u += 0x7fffu + ((u >> 16) & 1u);          // round-to-nearest-even
  return (unsigned short)(u >> 16);
}
__device__ __forceinline__ float bf2f(unsigned int h) {
  return __uint_as_float(h << 16);
}

typedef const __attribute__((address_space(1))) unsigned int GU32;
typedef __attribute__((address_space(3))) unsigned int LU32;
__device__ __forceinline__ void async16(const unsigned short* g, unsigned short* l) {
  __builtin_amdgcn_global_load_lds((GU32*)g, (LU32*)l, 16, 0, 0);
}

// ---------------- F / R decay scans -> bf16 tables with zero guard rows ----------------
// Fz: per batch 810 rows (stride KS): row 0 = 0, row 1+t = F[t].  Rz: row t = R[t], row 809 = 0.
__global__ __launch_bounds__(320) void k_scan(const float* __restrict__ doc,
                                              unsigned short* __restrict__ Fz,
                                              unsigned short* __restrict__ Rz)
{
  const int d  = threadIdx.x;
  const int t0 = blockIdx.x * 32;
  const int b  = blockIdx.y;
  const float* db = doc + (size_t)b * T_LEN * DD + d;
  if (blockIdx.z == 0) {
    if (blockIdx.x == 0) Fz[((size_t)b * 810) * KS + d] = 0;   // zero row
    if (d >= DD) return;
    int start = t0 - 192; if (start < 0) start = 0;
    int end = t0 + 31; if (end > T_LEN - 1) end = T_LEN - 1;
    float s = 0.f;
    for (int t = start; t <= end; ++t) {
      s = fmaf(0.9f, s, db[(size_t)t * DD]);
      if (t >= t0) Fz[((size_t)b * 810 + 1 + t) * KS + d] = f2bf(s);
    }
  } else {
    if (blockIdx.x == 0) Rz[((size_t)b * 810 + 809) * KS + d] = 0;  // zero row
    if (d >= DD) return;
    int t1 = t0 + 31; if (t1 > T_LEN - 1) t1 = T_LEN - 1;
    int start = t1 + 192; if (start > T_LEN - 1) start = T_LEN - 1;
    float s = 0.f;
    for (int t = start; t >= t0; --t) {
      s = fmaf(0.9f, s, db[(size_t)t * DD]);
      if (t <= t1) Rz[((size_t)b * 810 + t) * KS + d] = f2bf(s);
    }
  }
}

// ---------------- query FOFE ----------------
__global__ __launch_bounds__(320) void k_qf(const float* __restrict__ q, float* __restrict__ qf)
{
  const int d = threadIdx.x;
  const int b = blockIdx.x;
  if (d >= EE) return;
  float s = 0.f;
  for (int t = 0; t < LQ; ++t) s = fmaf(s, 0.9f, q[((size_t)b * LQ + t) * EE + d]);
  qf[b * EE + d] = s;
}

// ---------------- BN-folded split weights (fp32 -> bf16), one kernel ----------------
// j in [0,1024): Wlc lctx rows; [1024,2048): Wlc cand rows; [2048,3072): Wr rows.
__global__ __launch_bounds__(64) void k_w1split(const float* __restrict__ W1, const float* __restrict__ g1,
                                                const float* __restrict__ v1,
                                                unsigned short* __restrict__ Wlc,
                                                unsigned short* __restrict__ Wr)
{
  const int k = blockIdx.x * 64 + threadIdx.x;   // 0..319
  const int j = blockIdx.y;                      // 0..3071
  int jj, koff; unsigned short* dst; size_t idx;
  if (j < 1024)      { jj = j;        koff = k;       dst = Wlc; idx = (size_t)j * KS + k; }
  else if (j < 2048) { jj = j - 1024; koff = 304 + k; dst = Wlc; idx = (size_t)j * KS + k; }
  else               { jj = j - 2048; koff = 608 + k; dst = Wr;  idx = (size_t)(j - 2048) * KS + k; }
  float w = 0.f;
  if (k < 304) w = W1[(size_t)jj * CIN + koff] * g1[jj] * rsqrtf(v1[jj] + 1e-5f);
  dst[idx] = f2bf(w);
}
__global__ __launch_bounds__(64) void k_w2(const float* __restrict__ W2, const float* __restrict__ g2,
                                           const float* __restrict__ v2, unsigned short* __restrict__ W2b)
{
  const int k = blockIdx.x * 64 + threadIdx.x;
  const int j = blockIdx.y;
  float w = W2[(size_t)j * H1 + k] * g2[j] * rsqrtf(v2[j] + 1e-5f);
  W2b[(size_t)j * H1 + k] = f2bf(w);
}
__global__ __launch_bounds__(256) void k_bias2(const float* __restrict__ g2, const float* __restrict__ b2,
                                               const float* __restrict__ m2, const float* __restrict__ v2,
                                               float* __restrict__ bias2)
{
  const int i = blockIdx.x * 256 + threadIdx.x;
  if (i < H2) {
    float s = g2[i] * rsqrtf(v2[i] + 1e-5f);
    bias2[i] = b2[i] - m2[i] * s;
  }
}

// ---------------- base[b][j] = bias1'[j] + qf[b] . (s_j * W1[j, 912:1212]) ----------------
__global__ __launch_bounds__(256) void k_base(const float* __restrict__ W1, const float* __restrict__ g1,
                                              const float* __restrict__ b1, const float* __restrict__ m1,
                                              const float* __restrict__ v1, const float* __restrict__ qf,
                                              float* __restrict__ base)
{
  const int b = blockIdx.x;
  const int wv = threadIdx.x >> 6;
  const int lane = threadIdx.x & 63;
  const int j = blockIdx.y * 4 + wv;              // 0..1023
  const float* w = W1 + (size_t)j * CIN + 912;
  const float* q = qf + b * EE;
  float acc = 0.f;
  for (int k = lane; k < EE; k += 64) acc = fmaf(q[k], w[k], acc);
  #pragma unroll
  for (int off = 32; off; off >>= 1) acc += __shfl_down(acc, off);
  if (lane == 0) {
    const float sc = g1[j] * rsqrtf(v1[j] + 1e-5f);
    base[b * H1 + j] = b1[j] - m1[j] * sc + acc * sc;
  }
}

// ---------------- GEMM machinery ----------------
typedef __attribute__((ext_vector_type(8))) short frag8;
typedef __attribute__((ext_vector_type(4))) float f32x4;

// 128x128 tile, BK=32, 4 waves of 64x64.  Chunk-swizzled LDS to break the 8-way
// bank conflict: lane (lr,lc) FETCHES logical chunk lc^((lr>>1)&3); reader
// addresses physical chunk g^((row>>1)&3).  Swizzle is invariant under row+16.
#define GEMM_KLOOP(A_, B_, K_)                                                   \
  __shared__ __align__(16) unsigned short As[128 * 32];                          \
  __shared__ __align__(16) unsigned short Bs[128 * 32];                          \
  const int tid  = threadIdx.x;                                                  \
  const int lane = tid & 63;                                                     \
  const int wv   = tid >> 6;                                                     \
  const int wm   = wv & 1, wn = wv >> 1;                                         \
  const int lr = lane >> 2;                                                      \
  const int lc = lane & 3;                                                       \
  const int sc = lc ^ ((lr >> 1) & 3);                                           \
  const unsigned short* gA = A_ + ((size_t)bm * 128 + wv * 32 + lr) * K_ + sc * 8; \
  const unsigned short* gB = B_ + ((size_t)bn * 128 + wv * 32 + lr) * K_ + sc * 8; \
  const size_t row16 = (size_t)16 * K_;                                          \
  unsigned short* lA0 = &As[wv * 1024];                                          \
  unsigned short* lB0 = &Bs[wv * 1024];                                          \
  f32x4 acc[4][4];                                                               \
  _Pragma("unroll")                                                              \
  for (int i = 0; i < 4; ++i)                                                    \
    _Pragma("unroll")                                                            \
    for (int j = 0; j < 4; ++j) acc[i][j] = (f32x4){0.f, 0.f, 0.f, 0.f};         \
  const int arow = lane & 15;                                                    \
  const int pg   = (lane >> 4) ^ ((arow >> 1) & 3);                              \
  const int aoff = (wm * 64 + arow) * 32 + pg * 8;                               \
  const int boff = (wn * 64 + arow) * 32 + pg * 8;                               \
  for (int kc = 0; kc < K_; kc += 32) {                                          \
    __syncthreads();                                                             \
    async16(gA + kc,         lA0);                                               \
    async16(gA + kc + row16, lA0 + 512);                                         \
    async16(gB + kc,         lB0);                                               \
    async16(gB + kc + row16, lB0 + 512);                                         \
    __syncthreads();                                                             \
    frag8 a[4], b[4];                                                            \
    _Pragma("unroll")                                                            \
    for (int i = 0; i < 4; ++i) a[i] = *(const frag8*)&As[aoff + i * 512];       \
    _Pragma("unroll")                                                            \
    for (int i = 0; i < 4; ++i) b[i] = *(const frag8*)&Bs[boff + i * 512];       \
    _Pragma("unroll")                                                            \
    for (int i = 0; i < 4; ++i)                                                  \
      _Pragma("unroll")                                                          \
      for (int j = 0; j < 4; ++j)                                                \
        acc[i][j] = __builtin_amdgcn_mfma_f32_16x16x32_bf16(a[i], b[j], acc[i][j], 0, 0, 0); \
  }

// U-table GEMM, bf16 output: C = A * Bw^T
__global__ __launch_bounds__(256) void k_gemm_bf(const unsigned short* __restrict__ A,
                                                 const unsigned short* __restrict__ Bw,
                                                 unsigned short* __restrict__ C,
                                                 int K, int Nout)
{
  const int bn = blockIdx.x, bm = blockIdx.y;
  GEMM_KLOOP(A, Bw, K)
  const int crow0 = bm * 128 + wm * 64 + ((lane >> 4) << 2);
  const int ccol0 = bn * 128 + wn * 64 + (lane & 15);
  #pragma unroll
  for (int i = 0; i < 4; ++i)
    #pragma unroll
    for (int j = 0; j < 4; ++j) {
      const int col = ccol0 + j * 16;
      #pragma unroll
      for (int r = 0; r < 4; ++r)
        C[(size_t)(crow0 + i * 16 + r) * Nout + col] = f2bf(acc[i][j][r]);
    }
}

// ---------------- combine: h1 = relu(U_l[s] + U_c[e+1] - coef*U_c[s] + U_r[e+1] + base) ----------------
// XCD-swizzled flat grid (3240): xcd = bx&7 owns ~405 consecutive (b,s) pairs
// so its uce/ur rows (~2.5 MB) stay L2-resident per XCD.
__global__ __launch_bounds__(256) void k_combine(const unsigned short* __restrict__ UF,
                                                 const unsigned short* __restrict__ UR,
                                                 const float* __restrict__ base,
                                                 unsigned short* __restrict__ h1)
{
  const int flat = (blockIdx.x & 7) * 405 + (blockIdx.x >> 3);
  if (flat >= BATCH * T_LEN) return;
  const int b = flat / T_LEN;
  const int s = flat - b * T_LEN;
  const int half = threadIdx.x >> 7;   // 0/1: two span-rows in flight
  const int t = threadIdx.x & 127;     // 8-col group
  const size_t rs = (size_t)b * 810 + s;

  const uint4 ulp  = *(const uint4*)(UF + rs * 2048 + t * 8);
  const uint4 ucsp = *(const uint4*)(UF + rs * 2048 + 1024 + t * 8);
  const float4 b0 = *(const float4*)(base + b * H1 + t * 8);
  const float4 b1v = *(const float4*)(base + b * H1 + t * 8 + 4);
  float ul[8], ucs[8], bs[8];
  { const unsigned int* u = (const unsigned int*)&ulp;
    #pragma unroll
    for (int i = 0; i < 4; ++i) { ul[2*i] = bf2f(u[i] & 0xffff); ul[2*i+1] = bf2f(u[i] >> 16); } }
  { const unsigned int* u = (const unsigned int*)&ucsp;
    #pragma unroll
    for (int i = 0; i < 4; ++i) { ucs[2*i] = bf2f(u[i] & 0xffff); ucs[2*i+1] = bf2f(u[i] >> 16); } }
  bs[0]=b0.x; bs[1]=b0.y; bs[2]=b0.z; bs[3]=b0.w; bs[4]=b1v.x; bs[5]=b1v.y; bs[6]=b1v.z; bs[7]=b1v.w;

  const int nspan = min(16, T_LEN - s);
  int r0;
  if (s < 794) r0 = s * 16;
  else { const int d = s - 794; r0 = 12704 + 15 * d - (d * (d - 1)) / 2; }

  for (int sp = 0; sp < nspan; sp += 2) {
    const int row = sp + half;
    if (row < nspan) {
      const size_t re = rs + row + 1;
      const uint4 ucep = *(const uint4*)(UF + re * 2048 + 1024 + t * 8);
      const uint4 urp  = *(const uint4*)(UR + re * 1024 + t * 8);
      const float c = c_coef[row];
      const unsigned int* ue = (const unsigned int*)&ucep;
      const unsigned int* ur = (const unsigned int*)&urp;
      unsigned int o[4];
      #pragma unroll
      for (int i = 0; i < 4; ++i) {
        float xlo = ul[2*i]   + bf2f(ue[i] & 0xffff) - c * ucs[2*i]   + bf2f(ur[i] & 0xffff) + bs[2*i];
        float xhi = ul[2*i+1] + bf2f(ue[i] >> 16)    - c * ucs[2*i+1] + bf2f(ur[i] >> 16)    + bs[2*i+1];
        xlo = xlo > 0.f ? xlo : 0.f;
        xhi = xhi > 0.f ? xhi : 0.f;
        o[i] = (unsigned int)f2bf(xlo) | ((unsigned int)f2bf(xhi) << 16);
      }
      *(uint4*)(h1 + ((size_t)b * NPAD + r0 + row) * H1 + t * 8) = *(const uint4*)o;
    }
  }
}

// ---------------- GEMM2 + fused W3: BK=32 + swizzle, per-(row,bn) partials ----------------
__global__ __launch_bounds__(256) void k_gemm2p(const unsigned short* __restrict__ A,
                                                const unsigned short* __restrict__ W2b,
                                                const float* __restrict__ bias,
                                                const float* __restrict__ W3,
                                                float* __restrict__ P)
{
  const int global = blockIdx.x * 202 + blockIdx.y;   // xcd-contiguous bm range, bn fastest
  const int bm = global >> 2;
  const int bn = global & 3;
  __shared__ float red[2][4][4][4][2];                // [wm][i][r][grp][{p0,p1}]
  GEMM_KLOOP(A, W2b, H1)

  const int ccol0 = bn * 128 + wn * 64 + (lane & 15);
  float bj[4], w0[4], w1[4];
  #pragma unroll
  for (int j = 0; j < 4; ++j) {
    const int col = ccol0 + j * 16;
    bj[j] = bias[col];
    w0[j] = W3[col];
    w1[j] = W3[H2 + col];
  }
  float p0[4][4], p1[4][4];
  #pragma unroll
  for (int i = 0; i < 4; ++i)
    #pragma unroll
    for (int r = 0; r < 4; ++r) {
      float q0 = 0.f, q1 = 0.f;
      #pragma unroll
      for (int j = 0; j < 4; ++j) {
        float v = acc[i][j][r] + bj[j];
        v = v > 0.f ? v : 0.f;
        q0 = fmaf(v, w0[j], q0);
        q1 = fmaf(v, w1[j], q1);
      }
      #pragma unroll
      for (int m = 1; m < 16; m <<= 1) {
        q0 += __shfl_xor(q0, m);
        q1 += __shfl_xor(q1, m);
      }
      p0[i][r] = q0; p1[i][r] = q1;
    }

  const int grp = lane >> 4;
  if (wn == 1 && (lane & 15) == 0) {
    #pragma unroll
    for (int i = 0; i < 4; ++i)
      #pragma unroll
      for (int r = 0; r < 4; ++r) {
        red[wm][i][r][grp][0] = p0[i][r];
        red[wm][i][r][grp][1] = p1[i][r];
      }
  }
  __syncthreads();
  if (wn == 0 && (lane & 15) == 0) {
    #pragma unroll
    for (int i = 0; i < 4; ++i)
      #pragma unroll
      for (int r = 0; r < 4; ++r) {
        const size_t row = (size_t)bm * 128 + wm * 64 + grp * 4 + i * 16 + r;
        P[row * 8 + bn * 2 + 0] = p0[i][r] + red[wm][i][r][grp][0];
        P[row * 8 + bn * 2 + 1] = p1[i][r] + red[wm][i][r][grp][1];
      }
  }
}

// ---------------- final: sum 4 bn-partials per row -> out ----------------
__global__ __launch_bounds__(256) void k_fin(const float* __restrict__ P, float* __restrict__ out)
{
  const int row = blockIdx.x * 256 + threadIdx.x;
  if (row >= MROWS_F) return;
  const int b = row / NPAD;
  const int rr = row - b * NPAD;
  if (rr >= NCAND) return;
  const float4 pa = ((const float4*)P)[row * 2];
  const float4 pb = ((const float4*)P)[row * 2 + 1];
  float* o = out + ((size_t)b * NCAND + rr) * 2;
  o[0] = pa.x + pa.z + pb.x + pb.z;
  o[1] = pa.y + pa.w + pb.y + pb.w;
}

// ---------------- launch ----------------
extern "C" void kernel_launch(void* const* d_in, const int* in_sizes, int n_in,
                              void* d_out, int out_size, void* d_ws, size_t ws_size,
                              hipStream_t stream)
{
  const float* doc = (const float*)d_in[0];
  const float* qe  = (const float*)d_in[1];
  const float* W1  = (const float*)d_in[2];
  const float* g1  = (const float*)d_in[3];
  const float* b1  = (const float*)d_in[4];
  const float* m1  = (const float*)d_in[5];
  const float* v1  = (const float*)d_in[6];
  const float* W2  = (const float*)d_in[7];
  const float* g2  = (const float*)d_in[8];
  const float* b2  = (const float*)d_in[9];
  const float* m2  = (const float*)d_in[10];
  const float* v2  = (const float*)d_in[11];
  const float* W3  = (const float*)d_in[12];
  float* out = (float*)d_out;

  char* ws = (char*)d_ws;
  size_t off = 0;
  auto alloc = [&](size_t bytes) -> void* {
    void* p = ws + off;
    off = (off + bytes + 255) & ~(size_t)255;
    return p;
  };
  unsigned short* Fz    = (unsigned short*)alloc((size_t)TPAD * KS * 2);
  unsigned short* Rz    = (unsigned short*)alloc((size_t)TPAD * KS * 2);
  float*          qfbuf = (float*)alloc((size_t)BATCH * EE * 4);
  unsigned short* Wlc   = (unsigned short*)alloc((size_t)2048 * KS * 2);
  unsigned short* Wr    = (unsigned short*)alloc((size_t)1024 * KS * 2);
  unsigned short* W2b   = (unsigned short*)alloc((size_t)H2 * H1 * 2);
  float*          bias2 = (float*)alloc((size_t)H2 * 4);
  float*          base  = (float*)alloc((size_t)BATCH * H1 * 4);
  unsigned short* UF    = (unsigned short*)alloc((size_t)TPAD * 2048 * 2);
  unsigned short* UR    = (unsigned short*)alloc((size_t)TPAD * 1024 * 2);
  unsigned short* h1    = (unsigned short*)alloc((size_t)MROWS_F * H1 * 2);
  float*          P     = (float*)alloc((size_t)MROWS_F * 8 * 4);
  (void)ws_size;

  // prep
  k_scan<<<dim3(26, BATCH, 2), 320, 0, stream>>>(doc, Fz, Rz);
  k_qf<<<dim3(BATCH), 320, 0, stream>>>(qe, qfbuf);
  k_w1split<<<dim3(5, 3072), 64, 0, stream>>>(W1, g1, v1, Wlc, Wr);
  k_w2<<<dim3(16, H2), 64, 0, stream>>>(W2, g2, v2, W2b);
  k_bias2<<<dim3(2), 256, 0, stream>>>(g2, b2, m2, v2, bias2);
  k_base<<<dim3(BATCH, 256), 256, 0, stream>>>(W1, g1, b1, m1, v1, qfbuf, base);

  // U tables (bf16)
  k_gemm_bf<<<dim3(16, TPAD / 128), 256, 0, stream>>>(Fz, Wlc, UF, KS, 2048);
  k_gemm_bf<<<dim3(8, TPAD / 128), 256, 0, stream>>>(Rz, Wr, UR, KS, 1024);

  // gather-combine -> h1 (bf16)
  k_combine<<<dim3(8 * 405), 256, 0, stream>>>(UF, UR, base, h1);

  // GEMM2 with fused W3 partials, then reduce
  k_gemm2p<<<dim3(8, 202), 256, 0, stream>>>(h1, W2b, bias2, W3, P);
  k_fin<<<dim3((MROWS_F + 255) / 256), 256, 0, stream>>>(P, out);
}